// Round 2
// baseline (1453.138 us; speedup 1.0000x reference)
//
#include <hip/hip_runtime.h>

#define INF_F __builtin_inff()

typedef unsigned short u16;

__device__ __forceinline__ float b2f(u16 u) {
    union { unsigned int i; float f; } v; v.i = ((unsigned int)u) << 16; return v.f;
}
__device__ __forceinline__ u16 f2b(float f) {
    union { float f; unsigned int i; } v; v.f = f;
    unsigned int r = (v.i + 0x7FFFu + ((v.i >> 16) & 1u)) >> 16;
    return (u16)r;
}

// ---------------------------------------------------------------------------
// Tiled GEMM: C(bf16) = act(A' @ B [+ bias]); A'[r,k] = A[r,k]*scale[k]+shift[k]
// A: [M,K] row-major (lda), fp32 or bf16; B: [K,N] fp32 row-major; C: [M,N] bf16
// Requires: K%16==0, N%64==0, lda%4==0.
// ---------------------------------------------------------------------------
template<bool A_BF16, bool BN_A, bool BIAS, bool LRELU>
__launch_bounds__(256)
__global__ void k_gemm(const void* __restrict__ Av, int lda,
                       const float* __restrict__ B, int N,
                       u16* __restrict__ C, int M, int K,
                       const float* __restrict__ ascale, const float* __restrict__ ashift,
                       const float* __restrict__ bias, float slope)
{
    __shared__ float As[16][68];   // [k][row], pad keeps 16B align & breaks bank stride
    __shared__ float Bs[16][64];   // [k][col]
    const int tid = threadIdx.x;
    const int tx = tid & 15, ty = tid >> 4;
    const int row0 = blockIdx.y * 64;
    const int col0 = blockIdx.x * 64;
    const int ar = tid >> 2, ak = (tid & 3) << 2;   // A-tile load coords
    const int bc = (tid & 15) << 2, bk = tid >> 4;  // B-tile load coords
    float acc[4][4] = {};

    for (int k0 = 0; k0 < K; k0 += 16) {
        // ---- stage A tile (64 rows x 16 k) ----
        {
            int grow = row0 + ar;
            float4 v = make_float4(0.f, 0.f, 0.f, 0.f);
            if (grow < M) {
                if (A_BF16) {
                    const u16* A = (const u16*)Av;
                    ushort4 u = *reinterpret_cast<const ushort4*>(A + (size_t)grow * lda + k0 + ak);
                    v = make_float4(b2f(u.x), b2f(u.y), b2f(u.z), b2f(u.w));
                } else {
                    const float* A = (const float*)Av;
                    v = *reinterpret_cast<const float4*>(A + (size_t)grow * lda + k0 + ak);
                }
            }
            if (BN_A) {
                int kk = k0 + ak;
                v.x = fmaf(v.x, ascale[kk + 0], ashift[kk + 0]);
                v.y = fmaf(v.y, ascale[kk + 1], ashift[kk + 1]);
                v.z = fmaf(v.z, ascale[kk + 2], ashift[kk + 2]);
                v.w = fmaf(v.w, ascale[kk + 3], ashift[kk + 3]);
            }
            As[ak + 0][ar] = v.x;
            As[ak + 1][ar] = v.y;
            As[ak + 2][ar] = v.z;
            As[ak + 3][ar] = v.w;
        }
        // ---- stage B tile (16 k x 64 cols) ----
        {
            float4 v = *reinterpret_cast<const float4*>(B + (size_t)(k0 + bk) * N + col0 + bc);
            *reinterpret_cast<float4*>(&Bs[bk][bc]) = v;
        }
        __syncthreads();
        #pragma unroll
        for (int k = 0; k < 16; ++k) {
            float4 a = *reinterpret_cast<const float4*>(&As[k][ty << 2]);
            float4 b = *reinterpret_cast<const float4*>(&Bs[k][tx << 2]);
            float av[4] = {a.x, a.y, a.z, a.w};
            float bv[4] = {b.x, b.y, b.z, b.w};
            #pragma unroll
            for (int i = 0; i < 4; ++i)
                #pragma unroll
                for (int j = 0; j < 4; ++j)
                    acc[i][j] = fmaf(av[i], bv[j], acc[i][j]);
        }
        __syncthreads();
    }

    #pragma unroll
    for (int i = 0; i < 4; ++i) {
        int r = row0 + (ty << 2) + i;
        if (r >= M) continue;
        ushort4 o;
        u16* op = &o.x;
        #pragma unroll
        for (int j = 0; j < 4; ++j) {
            int c = col0 + (tx << 2) + j;
            float v = acc[i][j];
            if (BIAS)  v += bias[c];
            if (LRELU) v = v >= 0.f ? v : slope * v;
            op[j] = f2b(v);
        }
        *reinterpret_cast<ushort4*>(C + (size_t)r * N + col0 + (tx << 2)) = o;
    }
}

// ---------------------------------------------------------------------------
// Column stats over bf16 matrix: per-column sum & sumsq via atomics (for BN).
// ---------------------------------------------------------------------------
__launch_bounds__(256)
__global__ void k_colstats(const u16* __restrict__ X, int M, int C, int rows_per_block,
                           float* __restrict__ sum, float* __restrict__ sq)
{
    int r0 = blockIdx.x * rows_per_block;
    int r1 = min(M, r0 + rows_per_block);
    int c0 = threadIdx.x, c1 = threadIdx.x + 256;
    float s0 = 0.f, q0 = 0.f, s1 = 0.f, q1 = 0.f;
    for (int r = r0; r < r1; ++r) {
        const u16* row = X + (size_t)r * C;
        if (c0 < C) { float v = b2f(row[c0]); s0 += v; q0 += v * v; }
        if (c1 < C) { float v = b2f(row[c1]); s1 += v; q1 += v * v; }
    }
    if (c0 < C) { atomicAdd(&sum[c0], s0); atomicAdd(&sq[c0], q0); }
    if (c1 < C) { atomicAdd(&sum[c1], s1); atomicAdd(&sq[c1], q1); }
}

__global__ void k_bn_fin(const float* __restrict__ sum, const float* __restrict__ sq,
                         const float* __restrict__ g, const float* __restrict__ b,
                         int M, int C, float* __restrict__ scale, float* __restrict__ shift)
{
    int c = blockIdx.x * blockDim.x + threadIdx.x;
    if (c >= C) return;
    float mu  = sum[c] / (float)M;
    float var = sq[c] / (float)M - mu * mu;
    float sc  = g[c] * rsqrtf(var + 1e-5f);
    scale[c] = sc;
    shift[c] = b[c] - mu * sc;
}

// ---------------------------------------------------------------------------
// CSR build: count -> scan -> scatter
// ---------------------------------------------------------------------------
__launch_bounds__(256)
__global__ void k_count(const int* __restrict__ dst, int E, int* __restrict__ counts)
{
    int e = blockIdx.x * 256 + threadIdx.x;
    if (e < E) atomicAdd(&counts[dst[e]], 1);
}

__launch_bounds__(1024)
__global__ void k_scan(const int* __restrict__ counts, int* __restrict__ rowstart, int n)
{
    __shared__ int wsum[16];
    __shared__ int s_carry;
    int tid = threadIdx.x, lane = tid & 63, w = tid >> 6;
    if (tid == 0) { s_carry = 0; rowstart[0] = 0; }
    __syncthreads();
    for (int base = 0; base < n; base += 1024) {
        int carry = s_carry;
        int v = (base + tid < n) ? counts[base + tid] : 0;
        int x = v;
        #pragma unroll
        for (int off = 1; off < 64; off <<= 1) {
            int t = __shfl_up(x, off, 64);
            if (lane >= off) x += t;
        }
        if (lane == 63) wsum[w] = x;
        __syncthreads();
        int woff = 0;
        #pragma unroll
        for (int i = 0; i < 16; ++i)
            if (i < w) woff += wsum[i];
        int incl = carry + woff + x;
        if (base + tid < n) rowstart[base + tid + 1] = incl;
        __syncthreads();
        if (tid == 1023) s_carry = incl;   // = carry + chunk total (padding adds 0)
        __syncthreads();
    }
}

__launch_bounds__(256)
__global__ void k_scatter(const int* __restrict__ ei, int E,
                          const int* __restrict__ rowstart,
                          int* __restrict__ fill, int* __restrict__ csr)
{
    int e = blockIdx.x * 256 + threadIdx.x;
    if (e >= E) return;
    int s = ei[e], d = ei[E + e];
    int pos = rowstart[d] + atomicAdd(&fill[d], 1);
    csr[pos] = s;
}

// ---------------------------------------------------------------------------
// Per-(node,head) attention coefficients: <hp[n,h,:], a[h,:]> for a_src/a_dst.
// One wave per node; lane owns dims (2*lane, 2*lane+1) -> coalesced ushort2.
// ---------------------------------------------------------------------------
template<int HEADS>
__launch_bounds__(256)
__global__ void k_alpha(const u16* __restrict__ hp,
                        const float* __restrict__ aw_s, const float* __restrict__ aw_d,
                        float* __restrict__ as_o, float* __restrict__ ad_o, int Nn)
{
    int wv = (int)((blockIdx.x * (size_t)blockDim.x + threadIdx.x) >> 6);
    int lane = threadIdx.x & 63;
    if (wv >= Nn) return;
    int dim = lane * 2;
    #pragma unroll
    for (int h = 0; h < HEADS; ++h) {
        ushort2 u = *reinterpret_cast<const ushort2*>(hp + ((size_t)wv * HEADS + h) * 128 + dim);
        float x0 = b2f(u.x), x1 = b2f(u.y);
        float va = x0 * aw_s[h * 128 + dim] + x1 * aw_s[h * 128 + dim + 1];
        float vd = x0 * aw_d[h * 128 + dim] + x1 * aw_d[h * 128 + dim + 1];
        #pragma unroll
        for (int off = 32; off; off >>= 1) {
            va += __shfl_xor(va, off, 64);
            vd += __shfl_xor(vd, off, 64);
        }
        if (lane == 0) { as_o[wv * HEADS + h] = va; ad_o[wv * HEADS + h] = vd; }
    }
}

// ---------------------------------------------------------------------------
// GAT aggregation: one wave per (dst,head); flash-style online softmax over
// incoming edges; lane owns dims (2*lane, 2*lane+1). Adds bias + lrelu(0.01).
// ---------------------------------------------------------------------------
template<int HEADS>
__launch_bounds__(256)
__global__ void k_gat_agg(const u16* __restrict__ hp,
                          const float* __restrict__ as_, const float* __restrict__ ad_,
                          const int* __restrict__ rowstart, const int* __restrict__ csr,
                          const float* __restrict__ bias, u16* __restrict__ out, int Nn)
{
    int wv = (int)((blockIdx.x * (size_t)blockDim.x + threadIdx.x) >> 6);
    int lane = threadIdx.x & 63;
    int d = wv / HEADS, h = wv % HEADS;
    if (d >= Nn) return;
    int e0 = rowstart[d], e1 = rowstart[d + 1];
    float adv = ad_[(size_t)d * HEADS + h];
    int dim = lane * 2;
    float m = -INF_F, l = 0.f, acc0 = 0.f, acc1 = 0.f;
    for (int j = e0; j < e1; ++j) {
        int s = csr[j];
        float e = as_[(size_t)s * HEADS + h] + adv;
        e = e >= 0.f ? e : 0.2f * e;
        float mn = fmaxf(m, e);
        float rs = __expf(m - mn);   // first iter: exp(-inf)=0
        float w  = __expf(e - mn);
        ushort2 u = *reinterpret_cast<const ushort2*>(hp + ((size_t)s * HEADS + h) * 128 + dim);
        l    = l * rs + w;
        acc0 = acc0 * rs + w * b2f(u.x);
        acc1 = acc1 * rs + w * b2f(u.y);
        m = mn;
    }
    float inv = 1.f / (l + 1e-16f);
    float v0 = acc0 * inv + bias[h * 128 + dim];
    float v1 = acc1 * inv + bias[h * 128 + dim + 1];
    v0 = v0 >= 0.f ? v0 : 0.01f * v0;
    v1 = v1 >= 0.f ? v1 : 0.01f * v1;
    *reinterpret_cast<ushort2*>(out + ((size_t)d * HEADS + h) * 128 + dim) =
        make_ushort2(f2b(v0), f2b(v1));
}

// ---------------------------------------------------------------------------
// Final: z = [bn1(h1)|bn2(h2)|bn3(h3)] @ W + b, then log_softmax over 40 cols.
// BM=64 rows/block, all 40 cols in one block (padded to 64). out fp32.
// ---------------------------------------------------------------------------
__launch_bounds__(256)
__global__ void k_final(const u16* __restrict__ h1, const u16* __restrict__ h2,
                        const u16* __restrict__ h3,
                        const float* __restrict__ scale768, const float* __restrict__ shift768,
                        const float* __restrict__ W, const float* __restrict__ bias,
                        float* __restrict__ out, int M)
{
    __shared__ float As[16][68];
    __shared__ float Bs[16][64];
    const int tid = threadIdx.x;
    const int tx = tid & 15, ty = tid >> 4;
    const int row0 = blockIdx.x * 64;
    const int ar = tid >> 2, ak = (tid & 3) << 2;
    const int bc = (tid & 15) << 2, bk = tid >> 4;
    float acc[4][4] = {};

    for (int k0 = 0; k0 < 768; k0 += 16) {
        const u16* src; int ld, coff;
        if (k0 < 128)      { src = h1; ld = 128; coff = k0; }
        else if (k0 < 640) { src = h2; ld = 512; coff = k0 - 128; }
        else               { src = h3; ld = 128; coff = k0 - 640; }
        {
            int grow = row0 + ar;
            float4 v = make_float4(0.f, 0.f, 0.f, 0.f);
            if (grow < M) {
                ushort4 u = *reinterpret_cast<const ushort4*>(src + (size_t)grow * ld + coff + ak);
                v = make_float4(b2f(u.x), b2f(u.y), b2f(u.z), b2f(u.w));
            }
            int kk = k0 + ak;
            v.x = fmaf(v.x, scale768[kk + 0], shift768[kk + 0]);
            v.y = fmaf(v.y, scale768[kk + 1], shift768[kk + 1]);
            v.z = fmaf(v.z, scale768[kk + 2], shift768[kk + 2]);
            v.w = fmaf(v.w, scale768[kk + 3], shift768[kk + 3]);
            As[ak + 0][ar] = v.x;
            As[ak + 1][ar] = v.y;
            As[ak + 2][ar] = v.z;
            As[ak + 3][ar] = v.w;
        }
        {
            float4 v = make_float4(0.f, 0.f, 0.f, 0.f);
            if (bc < 40)   // cols 40..63 stay zero; W rows are 160B -> 16B aligned
                v = *reinterpret_cast<const float4*>(W + (size_t)(k0 + bk) * 40 + bc);
            *reinterpret_cast<float4*>(&Bs[bk][bc]) = v;
        }
        __syncthreads();
        #pragma unroll
        for (int k = 0; k < 16; ++k) {
            float4 a = *reinterpret_cast<const float4*>(&As[k][ty << 2]);
            float4 b = *reinterpret_cast<const float4*>(&Bs[k][tx << 2]);
            float av[4] = {a.x, a.y, a.z, a.w};
            float bv[4] = {b.x, b.y, b.z, b.w};
            #pragma unroll
            for (int i = 0; i < 4; ++i)
                #pragma unroll
                for (int j = 0; j < 4; ++j)
                    acc[i][j] = fmaf(av[i], bv[j], acc[i][j]);
        }
        __syncthreads();
    }

    // epilogue: bias + log_softmax across the 16 tx-threads (same wave)
    #pragma unroll
    for (int i = 0; i < 4; ++i) {
        float z[4];
        float mx = -INF_F;
        #pragma unroll
        for (int j = 0; j < 4; ++j) {
            int c = (tx << 2) + j;
            float v = acc[i][j] + (c < 40 ? bias[c] : 0.f);
            z[j] = (c < 40) ? v : -INF_F;
            mx = fmaxf(mx, z[j]);
        }
        #pragma unroll
        for (int off = 1; off < 16; off <<= 1) mx = fmaxf(mx, __shfl_xor(mx, off, 64));
        float se = 0.f;
        #pragma unroll
        for (int j = 0; j < 4; ++j) se += __expf(z[j] - mx);   // exp(-inf)=0 for pad
        #pragma unroll
        for (int off = 1; off < 16; off <<= 1) se += __shfl_xor(se, off, 64);
        float lse = mx + __logf(se);
        int r = row0 + (ty << 2) + i;
        if (r < M) {
            #pragma unroll
            for (int j = 0; j < 4; ++j) {
                int c = (tx << 2) + j;
                if (c < 40) out[(size_t)r * 40 + c] = z[j] - lse;
            }
        }
    }
}

// ---------------------------------------------------------------------------
extern "C" void kernel_launch(void* const* d_in, const int* in_sizes, int n_in,
                              void* d_out, int out_size, void* d_ws, size_t ws_size,
                              hipStream_t stream)
{
    const float* x     = (const float*)d_in[0];
    const int*   ei    = (const int*)  d_in[1];
    const float* fw_W  = (const float*)d_in[2];
    const float* fw_b  = (const float*)d_in[3];
    const float* c1_W  = (const float*)d_in[4];
    const float* c1_as = (const float*)d_in[5];
    const float* c1_ad = (const float*)d_in[6];
    const float* c1_b  = (const float*)d_in[7];
    const float* c2_W  = (const float*)d_in[8];
    const float* c2_as = (const float*)d_in[9];
    const float* c2_ad = (const float*)d_in[10];
    const float* c2_b  = (const float*)d_in[11];
    const float* bn1_g = (const float*)d_in[12];
    const float* bn1_b = (const float*)d_in[13];
    const float* bn2_g = (const float*)d_in[14];
    const float* bn2_b = (const float*)d_in[15];
    const float* bn3_g = (const float*)d_in[16];
    const float* bn3_b = (const float*)d_in[17];
    const float* l2_W  = (const float*)d_in[18];
    const float* l2_b  = (const float*)d_in[19];
    float* out = (float*)d_out;

    const int N = in_sizes[0] / 256;   // 50000
    const int E = in_sizes[1] / 2;     // 850000

    char* base = (char*)d_ws;
    size_t off = 0;
    auto alloc = [&](size_t bytes) -> void* {
        void* p = (void*)(base + off);
        off = (off + bytes + 255) & ~(size_t)255;
        return p;
    };
    // --- zeroed region (counts, fill, BN stats) must be first & contiguous ---
    int*   counts = (int*)  alloc((size_t)N * 4);
    int*   fill   = (int*)  alloc((size_t)N * 4);
    float* sum1   = (float*)alloc(128 * 4);
    float* sq1    = (float*)alloc(128 * 4);
    float* sum2   = (float*)alloc(512 * 4);
    float* sq2    = (float*)alloc(512 * 4);
    float* sum3   = (float*)alloc(128 * 4);
    float* sq3    = (float*)alloc(128 * 4);
    size_t zero_bytes = off;
    // --- rest (total workspace ~121 MB; bf16 activations, hp1 region reused) ---
    int*   rowstart = (int*)  alloc((size_t)(N + 1) * 4);
    int*   csr      = (int*)  alloc((size_t)E * 4);
    float* scale768 = (float*)alloc(768 * 4);
    float* shift768 = (float*)alloc(768 * 4);
    float* as1      = (float*)alloc((size_t)N * 4 * 4);
    float* ad1      = (float*)alloc((size_t)N * 4 * 4);
    float* as2      = (float*)alloc((size_t)N * 4);
    float* ad2      = (float*)alloc((size_t)N * 4);
    u16*   h1       = (u16*)  alloc((size_t)N * 128 * 2);
    u16*   h2       = (u16*)  alloc((size_t)N * 512 * 2);
    u16*   hp1      = (u16*)  alloc((size_t)N * 512 * 2);  // dead after agg1:
    u16*   hp2      = hp1;                                  //  reuse for hp2 [N,128]
    u16*   h3       = hp1 + (size_t)N * 128;                //  and h3 [N,128]
    (void)ws_size; (void)n_in; (void)out_size;

    const int mb = (N + 63) / 64;

    hipMemsetAsync(base, 0, zero_bytes, stream);

    // layer 1: h1 = lrelu(x @ fw_W + fw_b)
    k_gemm<false, false, true, true><<<dim3(2, mb), 256, 0, stream>>>(
        x, 256, fw_W, 128, h1, N, 256, nullptr, nullptr, fw_b, 0.01f);

    // CSR build (independent)
    k_count<<<(E + 255) / 256, 256, 0, stream>>>(ei + E, E, counts);
    k_scan<<<1, 1024, 0, stream>>>(counts, rowstart, N);
    k_scatter<<<(E + 255) / 256, 256, 0, stream>>>(ei, E, rowstart, fill, csr);

    // BN1
    k_colstats<<<(N + 511) / 512, 256, 0, stream>>>(h1, N, 128, 512, sum1, sq1);
    k_bn_fin<<<1, 128, 0, stream>>>(sum1, sq1, bn1_g, bn1_b, N, 128, scale768, shift768);

    // conv1 projection: hp1 = bn1(h1) @ c1_W   [N,512]
    k_gemm<true, true, false, false><<<dim3(8, mb), 256, 0, stream>>>(
        h1, 128, c1_W, 512, hp1, N, 128, scale768, shift768, nullptr, 0.f);
    k_alpha<4><<<(int)(((size_t)N * 64 + 255) / 256), 256, 0, stream>>>(
        hp1, c1_as, c1_ad, as1, ad1, N);
    k_gat_agg<4><<<(int)(((size_t)N * 4 * 64 + 255) / 256), 256, 0, stream>>>(
        hp1, as1, ad1, rowstart, csr, c1_b, h2, N);

    // BN2
    k_colstats<<<(N + 511) / 512, 256, 0, stream>>>(h2, N, 512, 512, sum2, sq2);
    k_bn_fin<<<1, 512, 0, stream>>>(sum2, sq2, bn2_g, bn2_b, N, 512, scale768 + 128, shift768 + 128);

    // conv2 projection: hp2 = bn2(h2) @ c2_W   [N,128]  (writes into dead hp1 region)
    k_gemm<true, true, false, false><<<dim3(2, mb), 256, 0, stream>>>(
        h2, 512, c2_W, 128, hp2, N, 512, scale768 + 128, shift768 + 128, nullptr, 0.f);
    k_alpha<1><<<(int)(((size_t)N * 64 + 255) / 256), 256, 0, stream>>>(
        hp2, c2_as, c2_ad, as2, ad2, N);
    k_gat_agg<1><<<(int)(((size_t)N * 64 + 255) / 256), 256, 0, stream>>>(
        hp2, as2, ad2, rowstart, csr, c2_b, h3, N);

    // BN3
    k_colstats<<<(N + 511) / 512, 256, 0, stream>>>(h3, N, 128, 512, sum3, sq3);
    k_bn_fin<<<1, 128, 0, stream>>>(sum3, sq3, bn3_g, bn3_b, N, 128, scale768 + 640, shift768 + 640);

    // final fused GEMM + log_softmax
    k_final<<<mb, 256, 0, stream>>>(h1, h2, h3, scale768, shift768, l2_W, l2_b, out, N);
}

// Round 3
// 1247.067 us; speedup vs baseline: 1.1652x; 1.1652x over previous
//
#include <hip/hip_runtime.h>

#define INF_F __builtin_inff()

typedef unsigned short u16;

__device__ __forceinline__ float b2f(u16 u) {
    union { unsigned int i; float f; } v; v.i = ((unsigned int)u) << 16; return v.f;
}
__device__ __forceinline__ u16 f2b(float f) {
    union { float f; unsigned int i; } v; v.f = f;
    unsigned int r = (v.i + 0x7FFFu + ((v.i >> 16) & 1u)) >> 16;
    return (u16)r;
}
// unpack a packed pair of bf16 (lo = bits[15:0], hi = bits[31:16])
__device__ __forceinline__ void bf2x(unsigned int p, float& lo, float& hi) {
    union { unsigned int i; float f; } a, b;
    a.i = p << 16; b.i = p & 0xFFFF0000u;
    lo = a.f; hi = b.f;
}
__device__ __forceinline__ unsigned int packbf(float lo, float hi) {
    return (unsigned int)f2b(lo) | ((unsigned int)f2b(hi) << 16);
}

// ---------------------------------------------------------------------------
// Tiled GEMM: C(bf16) = act(A' @ B [+ bias]); A'[r,k] = A[r,k]*scale[k]+shift[k]
// Optional fused attention-alpha epilogue: as_out[r*nheads+h] += sum_c acc*aw_s[c]
// (h = col0>>7; requires as_out/ad_out pre-zeroed; atomics).
// A: [M,K] row-major (lda), fp32 or bf16; B: [K,N] fp32 row-major; C: [M,N] bf16
// Requires: K%16==0, N%64==0, lda%4==0.
// ---------------------------------------------------------------------------
template<bool A_BF16, bool BN_A, bool BIAS, bool LRELU, bool ALPHA>
__launch_bounds__(256)
__global__ void k_gemm(const void* __restrict__ Av, int lda,
                       const float* __restrict__ B, int N,
                       u16* __restrict__ C, int M, int K,
                       const float* __restrict__ ascale, const float* __restrict__ ashift,
                       const float* __restrict__ bias, float slope,
                       const float* __restrict__ aw_s, const float* __restrict__ aw_d,
                       float* __restrict__ as_out, float* __restrict__ ad_out, int nheads)
{
    __shared__ float As[16][68];   // [k][row], pad keeps 16B align & breaks bank stride
    __shared__ float Bs[16][64];   // [k][col]
    const int tid = threadIdx.x;
    const int tx = tid & 15, ty = tid >> 4;
    const int row0 = blockIdx.y * 64;
    const int col0 = blockIdx.x * 64;
    const int ar = tid >> 2, ak = (tid & 3) << 2;   // A-tile load coords
    const int bc = (tid & 15) << 2, bk = tid >> 4;  // B-tile load coords
    float acc[4][4] = {};

    for (int k0 = 0; k0 < K; k0 += 16) {
        // ---- stage A tile (64 rows x 16 k) ----
        {
            int grow = row0 + ar;
            float4 v = make_float4(0.f, 0.f, 0.f, 0.f);
            if (grow < M) {
                if (A_BF16) {
                    const u16* A = (const u16*)Av;
                    ushort4 u = *reinterpret_cast<const ushort4*>(A + (size_t)grow * lda + k0 + ak);
                    v = make_float4(b2f(u.x), b2f(u.y), b2f(u.z), b2f(u.w));
                } else {
                    const float* A = (const float*)Av;
                    v = *reinterpret_cast<const float4*>(A + (size_t)grow * lda + k0 + ak);
                }
            }
            if (BN_A) {
                int kk = k0 + ak;
                v.x = fmaf(v.x, ascale[kk + 0], ashift[kk + 0]);
                v.y = fmaf(v.y, ascale[kk + 1], ashift[kk + 1]);
                v.z = fmaf(v.z, ascale[kk + 2], ashift[kk + 2]);
                v.w = fmaf(v.w, ascale[kk + 3], ashift[kk + 3]);
            }
            As[ak + 0][ar] = v.x;
            As[ak + 1][ar] = v.y;
            As[ak + 2][ar] = v.z;
            As[ak + 3][ar] = v.w;
        }
        // ---- stage B tile (16 k x 64 cols) ----
        {
            float4 v = *reinterpret_cast<const float4*>(B + (size_t)(k0 + bk) * N + col0 + bc);
            *reinterpret_cast<float4*>(&Bs[bk][bc]) = v;
        }
        __syncthreads();
        #pragma unroll
        for (int k = 0; k < 16; ++k) {
            float4 a = *reinterpret_cast<const float4*>(&As[k][ty << 2]);
            float4 b = *reinterpret_cast<const float4*>(&Bs[k][tx << 2]);
            float av[4] = {a.x, a.y, a.z, a.w};
            float bv[4] = {b.x, b.y, b.z, b.w};
            #pragma unroll
            for (int i = 0; i < 4; ++i)
                #pragma unroll
                for (int j = 0; j < 4; ++j)
                    acc[i][j] = fmaf(av[i], bv[j], acc[i][j]);
        }
        __syncthreads();
    }

    #pragma unroll
    for (int i = 0; i < 4; ++i) {
        int r = row0 + (ty << 2) + i;
        if (r >= M) continue;
        ushort4 o;
        u16* op = &o.x;
        #pragma unroll
        for (int j = 0; j < 4; ++j) {
            int c = col0 + (tx << 2) + j;
            float v = acc[i][j];
            if (BIAS)  v += bias[c];
            if (LRELU) v = v >= 0.f ? v : slope * v;
            op[j] = f2b(v);
        }
        *reinterpret_cast<ushort4*>(C + (size_t)r * N + col0 + (tx << 2)) = o;
    }

    if (ALPHA) {
        // h is constant per 64-col tile (64 | 128)
        const int h = col0 >> 7;
        #pragma unroll
        for (int i = 0; i < 4; ++i) {
            int r = row0 + (ty << 2) + i;
            float ps = 0.f, pd = 0.f;
            #pragma unroll
            for (int j = 0; j < 4; ++j) {
                int c = col0 + (tx << 2) + j;
                ps = fmaf(acc[i][j], aw_s[c], ps);
                pd = fmaf(acc[i][j], aw_d[c], pd);
            }
            #pragma unroll
            for (int off = 1; off < 16; off <<= 1) {
                ps += __shfl_xor(ps, off, 64);
                pd += __shfl_xor(pd, off, 64);
            }
            if (tx == 0 && r < M) {
                atomicAdd(&as_out[(size_t)r * nheads + h], ps);
                atomicAdd(&ad_out[(size_t)r * nheads + h], pd);
            }
        }
    }
}

// ---------------------------------------------------------------------------
// Column stats over bf16 matrix: per-column sum & sumsq via atomics (for BN).
// ---------------------------------------------------------------------------
__launch_bounds__(256)
__global__ void k_colstats(const u16* __restrict__ X, int M, int C, int rows_per_block,
                           float* __restrict__ sum, float* __restrict__ sq)
{
    int r0 = blockIdx.x * rows_per_block;
    int r1 = min(M, r0 + rows_per_block);
    int c0 = threadIdx.x, c1 = threadIdx.x + 256;
    float s0 = 0.f, q0 = 0.f, s1 = 0.f, q1 = 0.f;
    for (int r = r0; r < r1; ++r) {
        const u16* row = X + (size_t)r * C;
        if (c0 < C) { float v = b2f(row[c0]); s0 += v; q0 += v * v; }
        if (c1 < C) { float v = b2f(row[c1]); s1 += v; q1 += v * v; }
    }
    if (c0 < C) { atomicAdd(&sum[c0], s0); atomicAdd(&sq[c0], q0); }
    if (c1 < C) { atomicAdd(&sum[c1], s1); atomicAdd(&sq[c1], q1); }
}

__global__ void k_bn_fin(const float* __restrict__ sum, const float* __restrict__ sq,
                         const float* __restrict__ g, const float* __restrict__ b,
                         int M, int C, float* __restrict__ scale, float* __restrict__ shift)
{
    int c = blockIdx.x * blockDim.x + threadIdx.x;
    if (c >= C) return;
    float mu  = sum[c] / (float)M;
    float var = sq[c] / (float)M - mu * mu;
    float sc  = g[c] * rsqrtf(var + 1e-5f);
    scale[c] = sc;
    shift[c] = b[c] - mu * sc;
}

// ---------------------------------------------------------------------------
// CSR build: count -> scan -> scatter
// ---------------------------------------------------------------------------
__launch_bounds__(256)
__global__ void k_count(const int* __restrict__ dst, int E, int* __restrict__ counts)
{
    int e = blockIdx.x * 256 + threadIdx.x;
    if (e < E) atomicAdd(&counts[dst[e]], 1);
}

__launch_bounds__(1024)
__global__ void k_scan(const int* __restrict__ counts, int* __restrict__ rowstart, int n)
{
    __shared__ int wsum[16];
    __shared__ int s_carry;
    int tid = threadIdx.x, lane = tid & 63, w = tid >> 6;
    if (tid == 0) { s_carry = 0; rowstart[0] = 0; }
    __syncthreads();
    for (int base = 0; base < n; base += 1024) {
        int carry = s_carry;
        int v = (base + tid < n) ? counts[base + tid] : 0;
        int x = v;
        #pragma unroll
        for (int off = 1; off < 64; off <<= 1) {
            int t = __shfl_up(x, off, 64);
            if (lane >= off) x += t;
        }
        if (lane == 63) wsum[w] = x;
        __syncthreads();
        int woff = 0;
        #pragma unroll
        for (int i = 0; i < 16; ++i)
            if (i < w) woff += wsum[i];
        int incl = carry + woff + x;
        if (base + tid < n) rowstart[base + tid + 1] = incl;
        __syncthreads();
        if (tid == 1023) s_carry = incl;   // = carry + chunk total (padding adds 0)
        __syncthreads();
    }
}

__launch_bounds__(256)
__global__ void k_scatter(const int* __restrict__ ei, int E,
                          const int* __restrict__ rowstart,
                          int* __restrict__ fill, int* __restrict__ csr)
{
    int e = blockIdx.x * 256 + threadIdx.x;
    if (e >= E) return;
    int s = ei[e], d = ei[E + e];
    int pos = rowstart[d] + atomicAdd(&fill[d], 1);
    csr[pos] = s;
}

// ---------------------------------------------------------------------------
// GAT aggregation, HEADS=4: ONE wave per dst covers all heads.
// lane l: head = l>>4, dims (l&15)*8 .. +8  -> 16B/lane, 1KB coalesced per edge.
// Depth-2 software pipeline on the csr->as/hp dependent chain.
// ---------------------------------------------------------------------------
__launch_bounds__(256)
__global__ void k_gat_agg_h4(const u16* __restrict__ hp,
                             const float* __restrict__ as_, const float* __restrict__ ad_,
                             const int* __restrict__ rowstart, const int* __restrict__ csr,
                             const float* __restrict__ bias, u16* __restrict__ out, int Nn)
{
    int d = (int)((blockIdx.x * (size_t)blockDim.x + threadIdx.x) >> 6);
    int lane = threadIdx.x & 63;
    if (d >= Nn) return;
    const int h = lane >> 4;
    const int dim = (lane & 15) * 8;
    int e0 = rowstart[d], e1 = rowstart[d + 1];
    float adv = ad_[(size_t)d * 4 + h];
    float m = -INF_F, l = 0.f;
    float acc[8] = {};

    // prologue: prefetch edges e0 and e0+1
    int s0 = csr[e0];
    float a0 = as_[(size_t)s0 * 4 + h];
    uint4 u0 = *reinterpret_cast<const uint4*>(hp + ((size_t)s0 * 4 + h) * 128 + dim);
    float a1 = 0.f; uint4 u1 = u0;
    if (e0 + 1 < e1) {
        int s1 = csr[e0 + 1];
        a1 = as_[(size_t)s1 * 4 + h];
        u1 = *reinterpret_cast<const uint4*>(hp + ((size_t)s1 * 4 + h) * 128 + dim);
    }

    for (int j = e0; j < e1; ++j) {
        float e = a0 + adv;
        uint4 u = u0;
        a0 = a1; u0 = u1;
        if (j + 2 < e1) {
            int sn = csr[j + 2];
            a1 = as_[(size_t)sn * 4 + h];
            u1 = *reinterpret_cast<const uint4*>(hp + ((size_t)sn * 4 + h) * 128 + dim);
        }
        e = e >= 0.f ? e : 0.2f * e;
        float mn = fmaxf(m, e);
        float rs = __expf(m - mn);   // first iter: exp(-inf)=0
        float w  = __expf(e - mn);
        l = l * rs + w;
        float x[8];
        bf2x(u.x, x[0], x[1]);
        bf2x(u.y, x[2], x[3]);
        bf2x(u.z, x[4], x[5]);
        bf2x(u.w, x[6], x[7]);
        #pragma unroll
        for (int t = 0; t < 8; ++t) acc[t] = fmaf(acc[t], rs, w * x[t]);
        m = mn;
    }

    float inv = 1.f / (l + 1e-16f);
    const int ob = h * 128 + dim;
    float v[8];
    #pragma unroll
    for (int t = 0; t < 8; ++t) {
        float z = acc[t] * inv + bias[ob + t];
        v[t] = z >= 0.f ? z : 0.01f * z;
    }
    uint4 o;
    o.x = packbf(v[0], v[1]);
    o.y = packbf(v[2], v[3]);
    o.z = packbf(v[4], v[5]);
    o.w = packbf(v[6], v[7]);
    *reinterpret_cast<uint4*>(out + (size_t)d * 512 + ob) = o;
}

// ---------------------------------------------------------------------------
// GAT aggregation, HEADS=1: one wave per dst, lane owns 2 dims (4B/lane).
// Same depth-2 pipeline.
// ---------------------------------------------------------------------------
__launch_bounds__(256)
__global__ void k_gat_agg_h1(const u16* __restrict__ hp,
                             const float* __restrict__ as_, const float* __restrict__ ad_,
                             const int* __restrict__ rowstart, const int* __restrict__ csr,
                             const float* __restrict__ bias, u16* __restrict__ out, int Nn)
{
    int d = (int)((blockIdx.x * (size_t)blockDim.x + threadIdx.x) >> 6);
    int lane = threadIdx.x & 63;
    if (d >= Nn) return;
    const int dim = lane * 2;
    int e0 = rowstart[d], e1 = rowstart[d + 1];
    float adv = ad_[d];
    float m = -INF_F, l = 0.f, acc0 = 0.f, acc1 = 0.f;

    int s0 = csr[e0];
    float a0 = as_[s0];
    unsigned int u0 = *reinterpret_cast<const unsigned int*>(hp + (size_t)s0 * 128 + dim);
    float a1 = 0.f; unsigned int u1 = u0;
    if (e0 + 1 < e1) {
        int s1 = csr[e0 + 1];
        a1 = as_[s1];
        u1 = *reinterpret_cast<const unsigned int*>(hp + (size_t)s1 * 128 + dim);
    }

    for (int j = e0; j < e1; ++j) {
        float e = a0 + adv;
        unsigned int u = u0;
        a0 = a1; u0 = u1;
        if (j + 2 < e1) {
            int sn = csr[j + 2];
            a1 = as_[sn];
            u1 = *reinterpret_cast<const unsigned int*>(hp + (size_t)sn * 128 + dim);
        }
        e = e >= 0.f ? e : 0.2f * e;
        float mn = fmaxf(m, e);
        float rs = __expf(m - mn);
        float w  = __expf(e - mn);
        float x0, x1;
        bf2x(u, x0, x1);
        l    = l * rs + w;
        acc0 = fmaf(acc0, rs, w * x0);
        acc1 = fmaf(acc1, rs, w * x1);
        m = mn;
    }

    float inv = 1.f / (l + 1e-16f);
    float v0 = acc0 * inv + bias[dim];
    float v1 = acc1 * inv + bias[dim + 1];
    v0 = v0 >= 0.f ? v0 : 0.01f * v0;
    v1 = v1 >= 0.f ? v1 : 0.01f * v1;
    *reinterpret_cast<unsigned int*>(out + (size_t)d * 128 + dim) = packbf(v0, v1);
}

// ---------------------------------------------------------------------------
// Final: z = [bn1(h1)|bn2(h2)|bn3(h3)] @ W + b, then log_softmax over 40 cols.
// BM=64 rows/block, all 40 cols in one block (padded to 64). out fp32.
// ---------------------------------------------------------------------------
__launch_bounds__(256)
__global__ void k_final(const u16* __restrict__ h1, const u16* __restrict__ h2,
                        const u16* __restrict__ h3,
                        const float* __restrict__ scale768, const float* __restrict__ shift768,
                        const float* __restrict__ W, const float* __restrict__ bias,
                        float* __restrict__ out, int M)
{
    __shared__ float As[16][68];
    __shared__ float Bs[16][64];
    const int tid = threadIdx.x;
    const int tx = tid & 15, ty = tid >> 4;
    const int row0 = blockIdx.x * 64;
    const int ar = tid >> 2, ak = (tid & 3) << 2;
    const int bc = (tid & 15) << 2, bk = tid >> 4;
    float acc[4][4] = {};

    for (int k0 = 0; k0 < 768; k0 += 16) {
        const u16* src; int ld, coff;
        if (k0 < 128)      { src = h1; ld = 128; coff = k0; }
        else if (k0 < 640) { src = h2; ld = 512; coff = k0 - 128; }
        else               { src = h3; ld = 128; coff = k0 - 640; }
        {
            int grow = row0 + ar;
            float4 v = make_float4(0.f, 0.f, 0.f, 0.f);
            if (grow < M) {
                ushort4 u = *reinterpret_cast<const ushort4*>(src + (size_t)grow * ld + coff + ak);
                v = make_float4(b2f(u.x), b2f(u.y), b2f(u.z), b2f(u.w));
            }
            int kk = k0 + ak;
            v.x = fmaf(v.x, scale768[kk + 0], shift768[kk + 0]);
            v.y = fmaf(v.y, scale768[kk + 1], shift768[kk + 1]);
            v.z = fmaf(v.z, scale768[kk + 2], shift768[kk + 2]);
            v.w = fmaf(v.w, scale768[kk + 3], shift768[kk + 3]);
            As[ak + 0][ar] = v.x;
            As[ak + 1][ar] = v.y;
            As[ak + 2][ar] = v.z;
            As[ak + 3][ar] = v.w;
        }
        {
            float4 v = make_float4(0.f, 0.f, 0.f, 0.f);
            if (bc < 40)   // cols 40..63 stay zero; W rows are 160B -> 16B aligned
                v = *reinterpret_cast<const float4*>(W + (size_t)(k0 + bk) * 40 + bc);
            *reinterpret_cast<float4*>(&Bs[bk][bc]) = v;
        }
        __syncthreads();
        #pragma unroll
        for (int k = 0; k < 16; ++k) {
            float4 a = *reinterpret_cast<const float4*>(&As[k][ty << 2]);
            float4 b = *reinterpret_cast<const float4*>(&Bs[k][tx << 2]);
            float av[4] = {a.x, a.y, a.z, a.w};
            float bv[4] = {b.x, b.y, b.z, b.w};
            #pragma unroll
            for (int i = 0; i < 4; ++i)
                #pragma unroll
                for (int j = 0; j < 4; ++j)
                    acc[i][j] = fmaf(av[i], bv[j], acc[i][j]);
        }
        __syncthreads();
    }

    // epilogue: bias + log_softmax across the 16 tx-threads (same wave)
    #pragma unroll
    for (int i = 0; i < 4; ++i) {
        float z[4];
        float mx = -INF_F;
        #pragma unroll
        for (int j = 0; j < 4; ++j) {
            int c = (tx << 2) + j;
            float v = acc[i][j] + (c < 40 ? bias[c] : 0.f);
            z[j] = (c < 40) ? v : -INF_F;
            mx = fmaxf(mx, z[j]);
        }
        #pragma unroll
        for (int off = 1; off < 16; off <<= 1) mx = fmaxf(mx, __shfl_xor(mx, off, 64));
        float se = 0.f;
        #pragma unroll
        for (int j = 0; j < 4; ++j) se += __expf(z[j] - mx);   // exp(-inf)=0 for pad
        #pragma unroll
        for (int off = 1; off < 16; off <<= 1) se += __shfl_xor(se, off, 64);
        float lse = mx + __logf(se);
        int r = row0 + (ty << 2) + i;
        if (r < M) {
            #pragma unroll
            for (int j = 0; j < 4; ++j) {
                int c = (tx << 2) + j;
                if (c < 40) out[(size_t)r * 40 + c] = z[j] - lse;
            }
        }
    }
}

// ---------------------------------------------------------------------------
extern "C" void kernel_launch(void* const* d_in, const int* in_sizes, int n_in,
                              void* d_out, int out_size, void* d_ws, size_t ws_size,
                              hipStream_t stream)
{
    const float* x     = (const float*)d_in[0];
    const int*   ei    = (const int*)  d_in[1];
    const float* fw_W  = (const float*)d_in[2];
    const float* fw_b  = (const float*)d_in[3];
    const float* c1_W  = (const float*)d_in[4];
    const float* c1_as = (const float*)d_in[5];
    const float* c1_ad = (const float*)d_in[6];
    const float* c1_b  = (const float*)d_in[7];
    const float* c2_W  = (const float*)d_in[8];
    const float* c2_as = (const float*)d_in[9];
    const float* c2_ad = (const float*)d_in[10];
    const float* c2_b  = (const float*)d_in[11];
    const float* bn1_g = (const float*)d_in[12];
    const float* bn1_b = (const float*)d_in[13];
    const float* bn2_g = (const float*)d_in[14];
    const float* bn2_b = (const float*)d_in[15];
    const float* bn3_g = (const float*)d_in[16];
    const float* bn3_b = (const float*)d_in[17];
    const float* l2_W  = (const float*)d_in[18];
    const float* l2_b  = (const float*)d_in[19];
    float* out = (float*)d_out;

    const int N = in_sizes[0] / 256;   // 50000
    const int E = in_sizes[1] / 2;     // 850000

    char* base = (char*)d_ws;
    size_t off = 0;
    auto alloc = [&](size_t bytes) -> void* {
        void* p = (void*)(base + off);
        off = (off + bytes + 255) & ~(size_t)255;
        return p;
    };
    // --- zeroed region (counts, fill, BN stats, alpha accumulators) ---
    int*   counts = (int*)  alloc((size_t)N * 4);
    int*   fill   = (int*)  alloc((size_t)N * 4);
    float* sum1   = (float*)alloc(128 * 4);
    float* sq1    = (float*)alloc(128 * 4);
    float* sum2   = (float*)alloc(512 * 4);
    float* sq2    = (float*)alloc(512 * 4);
    float* sum3   = (float*)alloc(128 * 4);
    float* sq3    = (float*)alloc(128 * 4);
    float* as1    = (float*)alloc((size_t)N * 4 * 4);
    float* ad1    = (float*)alloc((size_t)N * 4 * 4);
    float* as2    = (float*)alloc((size_t)N * 4);
    float* ad2    = (float*)alloc((size_t)N * 4);
    size_t zero_bytes = off;
    // --- rest (bf16 activations; hp1 region reused for hp2/h3) ---
    int*   rowstart = (int*)  alloc((size_t)(N + 1) * 4);
    int*   csr      = (int*)  alloc((size_t)E * 4);
    float* scale768 = (float*)alloc(768 * 4);
    float* shift768 = (float*)alloc(768 * 4);
    u16*   h1       = (u16*)  alloc((size_t)N * 128 * 2);
    u16*   h2       = (u16*)  alloc((size_t)N * 512 * 2);
    u16*   hp1      = (u16*)  alloc((size_t)N * 512 * 2);  // dead after agg1:
    u16*   hp2      = hp1;                                  //  reuse for hp2 [N,128]
    u16*   h3       = hp1 + (size_t)N * 128;                //  and h3 [N,128]
    (void)ws_size; (void)n_in; (void)out_size;

    const int mb = (N + 63) / 64;
    const int wave_blocks = (int)(((size_t)N * 64 + 255) / 256);

    hipMemsetAsync(base, 0, zero_bytes, stream);

    // layer 1: h1 = lrelu(x @ fw_W + fw_b)
    k_gemm<false, false, true, true, false><<<dim3(2, mb), 256, 0, stream>>>(
        x, 256, fw_W, 128, h1, N, 256, nullptr, nullptr, fw_b, 0.01f,
        nullptr, nullptr, nullptr, nullptr, 0);

    // CSR build (independent)
    k_count<<<(E + 255) / 256, 256, 0, stream>>>(ei + E, E, counts);
    k_scan<<<1, 1024, 0, stream>>>(counts, rowstart, N);
    k_scatter<<<(E + 255) / 256, 256, 0, stream>>>(ei, E, rowstart, fill, csr);

    // BN1
    k_colstats<<<(N + 511) / 512, 256, 0, stream>>>(h1, N, 128, 512, sum1, sq1);
    k_bn_fin<<<1, 128, 0, stream>>>(sum1, sq1, bn1_g, bn1_b, N, 128, scale768, shift768);

    // conv1 projection: hp1 = bn1(h1) @ c1_W  [N,512], alpha fused into epilogue
    k_gemm<true, true, false, false, true><<<dim3(8, mb), 256, 0, stream>>>(
        h1, 128, c1_W, 512, hp1, N, 128, scale768, shift768, nullptr, 0.f,
        c1_as, c1_ad, as1, ad1, 4);
    k_gat_agg_h4<<<wave_blocks, 256, 0, stream>>>(
        hp1, as1, ad1, rowstart, csr, c1_b, h2, N);

    // BN2
    k_colstats<<<(N + 511) / 512, 256, 0, stream>>>(h2, N, 512, 512, sum2, sq2);
    k_bn_fin<<<1, 512, 0, stream>>>(sum2, sq2, bn2_g, bn2_b, N, 512, scale768 + 128, shift768 + 128);

    // conv2 projection: hp2 = bn2(h2) @ c2_W  [N,128] (into dead hp1 region)
    k_gemm<true, true, false, false, true><<<dim3(2, mb), 256, 0, stream>>>(
        h2, 512, c2_W, 128, hp2, N, 512, scale768 + 128, shift768 + 128, nullptr, 0.f,
        c2_as, c2_ad, as2, ad2, 1);
    k_gat_agg_h1<<<wave_blocks, 256, 0, stream>>>(
        hp2, as2, ad2, rowstart, csr, c2_b, h3, N);

    // BN3
    k_colstats<<<(N + 511) / 512, 256, 0, stream>>>(h3, N, 128, 512, sum3, sq3);
    k_bn_fin<<<1, 128, 0, stream>>>(sum3, sq3, bn3_g, bn3_b, N, 128, scale768 + 640, shift768 + 640);

    // final fused GEMM + log_softmax
    k_final<<<mb, 256, 0, stream>>>(h1, h2, h3, scale768, shift768, l2_W, l2_b, out, N);
}

// Round 4
// 745.661 us; speedup vs baseline: 1.9488x; 1.6724x over previous
//
#include <hip/hip_runtime.h>

#define INF_F __builtin_inff()

typedef unsigned short u16;

__device__ __forceinline__ float b2f(u16 u) {
    union { unsigned int i; float f; } v; v.i = ((unsigned int)u) << 16; return v.f;
}
__device__ __forceinline__ u16 f2b(float f) {
    union { float f; unsigned int i; } v; v.f = f;
    unsigned int r = (v.i + 0x7FFFu + ((v.i >> 16) & 1u)) >> 16;
    return (u16)r;
}
// unpack a packed pair of bf16 (lo = bits[15:0], hi = bits[31:16])
__device__ __forceinline__ void bf2x(unsigned int p, float& lo, float& hi) {
    union { unsigned int i; float f; } a, b;
    a.i = p << 16; b.i = p & 0xFFFF0000u;
    lo = a.f; hi = b.f;
}
__device__ __forceinline__ unsigned int packbf(float lo, float hi) {
    return (unsigned int)f2b(lo) | ((unsigned int)f2b(hi) << 16);
}

// ---------------------------------------------------------------------------
// Tiled GEMM: C(bf16) = act(A' @ B [+ bias]); A'[r,k] = A[r,k]*scale[k]+shift[k]
// Optional fused attention-alpha epilogue: as_out[r*nheads+h] += sum_c acc*aw_s[c]
// (h = col0>>7; requires as_out/ad_out pre-zeroed; atomics).
// A: [M,K] row-major (lda), fp32 or bf16; B: [K,N] fp32 row-major; C: [M,N] bf16
// Requires: K%16==0, N%64==0, lda%4==0.
// ---------------------------------------------------------------------------
template<bool A_BF16, bool BN_A, bool BIAS, bool LRELU, bool ALPHA>
__launch_bounds__(256)
__global__ void k_gemm(const void* __restrict__ Av, int lda,
                       const float* __restrict__ B, int N,
                       u16* __restrict__ C, int M, int K,
                       const float* __restrict__ ascale, const float* __restrict__ ashift,
                       const float* __restrict__ bias, float slope,
                       const float* __restrict__ aw_s, const float* __restrict__ aw_d,
                       float* __restrict__ as_out, float* __restrict__ ad_out, int nheads)
{
    __shared__ float As[16][68];   // [k][row], pad keeps 16B align & breaks bank stride
    __shared__ float Bs[16][64];   // [k][col]
    const int tid = threadIdx.x;
    const int tx = tid & 15, ty = tid >> 4;
    const int row0 = blockIdx.y * 64;
    const int col0 = blockIdx.x * 64;
    const int ar = tid >> 2, ak = (tid & 3) << 2;   // A-tile load coords
    const int bc = (tid & 15) << 2, bk = tid >> 4;  // B-tile load coords
    float acc[4][4] = {};

    for (int k0 = 0; k0 < K; k0 += 16) {
        // ---- stage A tile (64 rows x 16 k) ----
        {
            int grow = row0 + ar;
            float4 v = make_float4(0.f, 0.f, 0.f, 0.f);
            if (grow < M) {
                if (A_BF16) {
                    const u16* A = (const u16*)Av;
                    ushort4 u = *reinterpret_cast<const ushort4*>(A + (size_t)grow * lda + k0 + ak);
                    v = make_float4(b2f(u.x), b2f(u.y), b2f(u.z), b2f(u.w));
                } else {
                    const float* A = (const float*)Av;
                    v = *reinterpret_cast<const float4*>(A + (size_t)grow * lda + k0 + ak);
                }
            }
            if (BN_A) {
                int kk = k0 + ak;
                v.x = fmaf(v.x, ascale[kk + 0], ashift[kk + 0]);
                v.y = fmaf(v.y, ascale[kk + 1], ashift[kk + 1]);
                v.z = fmaf(v.z, ascale[kk + 2], ashift[kk + 2]);
                v.w = fmaf(v.w, ascale[kk + 3], ashift[kk + 3]);
            }
            As[ak + 0][ar] = v.x;
            As[ak + 1][ar] = v.y;
            As[ak + 2][ar] = v.z;
            As[ak + 3][ar] = v.w;
        }
        // ---- stage B tile (16 k x 64 cols) ----
        {
            float4 v = *reinterpret_cast<const float4*>(B + (size_t)(k0 + bk) * N + col0 + bc);
            *reinterpret_cast<float4*>(&Bs[bk][bc]) = v;
        }
        __syncthreads();
        #pragma unroll
        for (int k = 0; k < 16; ++k) {
            float4 a = *reinterpret_cast<const float4*>(&As[k][ty << 2]);
            float4 b = *reinterpret_cast<const float4*>(&Bs[k][tx << 2]);
            float av[4] = {a.x, a.y, a.z, a.w};
            float bv[4] = {b.x, b.y, b.z, b.w};
            #pragma unroll
            for (int i = 0; i < 4; ++i)
                #pragma unroll
                for (int j = 0; j < 4; ++j)
                    acc[i][j] = fmaf(av[i], bv[j], acc[i][j]);
        }
        __syncthreads();
    }

    #pragma unroll
    for (int i = 0; i < 4; ++i) {
        int r = row0 + (ty << 2) + i;
        if (r >= M) continue;
        ushort4 o;
        u16* op = &o.x;
        #pragma unroll
        for (int j = 0; j < 4; ++j) {
            int c = col0 + (tx << 2) + j;
            float v = acc[i][j];
            if (BIAS)  v += bias[c];
            if (LRELU) v = v >= 0.f ? v : slope * v;
            op[j] = f2b(v);
        }
        *reinterpret_cast<ushort4*>(C + (size_t)r * N + col0 + (tx << 2)) = o;
    }

    if (ALPHA) {
        // h is constant per 64-col tile (64 | 128)
        const int h = col0 >> 7;
        #pragma unroll
        for (int i = 0; i < 4; ++i) {
            int r = row0 + (ty << 2) + i;
            float ps = 0.f, pd = 0.f;
            #pragma unroll
            for (int j = 0; j < 4; ++j) {
                int c = col0 + (tx << 2) + j;
                ps = fmaf(acc[i][j], aw_s[c], ps);
                pd = fmaf(acc[i][j], aw_d[c], pd);
            }
            #pragma unroll
            for (int off = 1; off < 16; off <<= 1) {
                ps += __shfl_xor(ps, off, 64);
                pd += __shfl_xor(pd, off, 64);
            }
            if (tx == 0 && r < M) {
                atomicAdd(&as_out[(size_t)r * nheads + h], ps);
                atomicAdd(&ad_out[(size_t)r * nheads + h], pd);
            }
        }
    }
}

// ---------------------------------------------------------------------------
// BN stats stage 1: per-block column partial sums/sumsq of bf16 matrix.
// Grid: NB blocks x 256 thr. Thread owns a fixed 8-column group (uint4/16B
// loads, fully coalesced: at C=512 one wave = one full row). LDS layout [8][256]
// for conflict-free transpose-reduce. Writes psum/psq[b*C+c] (no atomics).
// Requires C%8==0, C<=2048.
// ---------------------------------------------------------------------------
__launch_bounds__(256)
__global__ void k_colstats(const u16* __restrict__ X, int M, int C,
                           float* __restrict__ psum, float* __restrict__ psq)
{
    const int CG  = C >> 3;        // column groups of 8
    const int RPI = 256 / CG;      // rows per iteration
    const int tid = threadIdx.x;
    const int cg  = tid & (CG - 1);
    const int ro  = tid / CG;
    const int nb  = gridDim.x;
    const int rows_chunk = (M + nb - 1) / nb;
    const int r0 = blockIdx.x * rows_chunk;
    const int r1 = min(M, r0 + rows_chunk);

    float s[8] = {}, q[8] = {};
    for (int r = r0 + ro; r < r1; r += RPI) {
        uint4 u = *reinterpret_cast<const uint4*>(X + (size_t)r * C + cg * 8);
        float x[8];
        bf2x(u.x, x[0], x[1]);
        bf2x(u.y, x[2], x[3]);
        bf2x(u.z, x[4], x[5]);
        bf2x(u.w, x[6], x[7]);
        #pragma unroll
        for (int j = 0; j < 8; ++j) { s[j] += x[j]; q[j] = fmaf(x[j], x[j], q[j]); }
    }

    __shared__ float lsum[8][256];
    __shared__ float lsq [8][256];
    #pragma unroll
    for (int j = 0; j < 8; ++j) { lsum[j][tid] = s[j]; lsq[j][tid] = q[j]; }
    __syncthreads();

    if (tid < CG) {
        #pragma unroll
        for (int j = 0; j < 8; ++j) {
            float ss = 0.f, qq = 0.f;
            for (int o = 0; o < RPI; ++o) {
                ss += lsum[j][o * CG + tid];
                qq += lsq [j][o * CG + tid];
            }
            psum[(size_t)blockIdx.x * C + tid * 8 + j] = ss;
            psq [(size_t)blockIdx.x * C + tid * 8 + j] = qq;
        }
    }
}

// ---------------------------------------------------------------------------
// BN stats stage 2: reduce NB partials per column, emit folded scale/shift.
// One wave per column.
// ---------------------------------------------------------------------------
__launch_bounds__(256)
__global__ void k_colred(const float* __restrict__ psum, const float* __restrict__ psq,
                         const float* __restrict__ g, const float* __restrict__ b,
                         int nb, int M, int C,
                         float* __restrict__ scale, float* __restrict__ shift)
{
    int c = blockIdx.x * 4 + (threadIdx.x >> 6);
    int lane = threadIdx.x & 63;
    if (c >= C) return;
    float s = 0.f, q = 0.f;
    for (int l = lane; l < nb; l += 64) {
        s += psum[(size_t)l * C + c];
        q += psq [(size_t)l * C + c];
    }
    #pragma unroll
    for (int off = 32; off; off >>= 1) {
        s += __shfl_xor(s, off, 64);
        q += __shfl_xor(q, off, 64);
    }
    if (lane == 0) {
        float mu  = s / (float)M;
        float var = q / (float)M - mu * mu;
        float sc  = g[c] * rsqrtf(var + 1e-5f);
        scale[c] = sc;
        shift[c] = b[c] - mu * sc;
    }
}

// ---------------------------------------------------------------------------
// CSR build: count -> scan -> scatter
// ---------------------------------------------------------------------------
__launch_bounds__(256)
__global__ void k_count(const int* __restrict__ dst, int E, int* __restrict__ counts)
{
    int e = blockIdx.x * 256 + threadIdx.x;
    if (e < E) atomicAdd(&counts[dst[e]], 1);
}

__launch_bounds__(1024)
__global__ void k_scan(const int* __restrict__ counts, int* __restrict__ rowstart, int n)
{
    __shared__ int wsum[16];
    __shared__ int s_carry;
    int tid = threadIdx.x, lane = tid & 63, w = tid >> 6;
    if (tid == 0) { s_carry = 0; rowstart[0] = 0; }
    __syncthreads();
    for (int base = 0; base < n; base += 1024) {
        int carry = s_carry;
        int v = (base + tid < n) ? counts[base + tid] : 0;
        int x = v;
        #pragma unroll
        for (int off = 1; off < 64; off <<= 1) {
            int t = __shfl_up(x, off, 64);
            if (lane >= off) x += t;
        }
        if (lane == 63) wsum[w] = x;
        __syncthreads();
        int woff = 0;
        #pragma unroll
        for (int i = 0; i < 16; ++i)
            if (i < w) woff += wsum[i];
        int incl = carry + woff + x;
        if (base + tid < n) rowstart[base + tid + 1] = incl;
        __syncthreads();
        if (tid == 1023) s_carry = incl;   // = carry + chunk total (padding adds 0)
        __syncthreads();
    }
}

__launch_bounds__(256)
__global__ void k_scatter(const int* __restrict__ ei, int E,
                          const int* __restrict__ rowstart,
                          int* __restrict__ fill, int* __restrict__ csr)
{
    int e = blockIdx.x * 256 + threadIdx.x;
    if (e >= E) return;
    int s = ei[e], d = ei[E + e];
    int pos = rowstart[d] + atomicAdd(&fill[d], 1);
    csr[pos] = s;
}

// ---------------------------------------------------------------------------
// GAT aggregation, HEADS=4: ONE wave per dst covers all heads.
// lane l: head = l>>4, dims (l&15)*8 .. +8  -> 16B/lane, 1KB coalesced per edge.
// Depth-2 software pipeline on the csr->as/hp dependent chain.
// ---------------------------------------------------------------------------
__launch_bounds__(256)
__global__ void k_gat_agg_h4(const u16* __restrict__ hp,
                             const float* __restrict__ as_, const float* __restrict__ ad_,
                             const int* __restrict__ rowstart, const int* __restrict__ csr,
                             const float* __restrict__ bias, u16* __restrict__ out, int Nn)
{
    int d = (int)((blockIdx.x * (size_t)blockDim.x + threadIdx.x) >> 6);
    int lane = threadIdx.x & 63;
    if (d >= Nn) return;
    const int h = lane >> 4;
    const int dim = (lane & 15) * 8;
    int e0 = rowstart[d], e1 = rowstart[d + 1];
    float adv = ad_[(size_t)d * 4 + h];
    float m = -INF_F, l = 0.f;
    float acc[8] = {};

    // prologue: prefetch edges e0 and e0+1
    int s0 = csr[e0];
    float a0 = as_[(size_t)s0 * 4 + h];
    uint4 u0 = *reinterpret_cast<const uint4*>(hp + ((size_t)s0 * 4 + h) * 128 + dim);
    float a1 = 0.f; uint4 u1 = u0;
    if (e0 + 1 < e1) {
        int s1 = csr[e0 + 1];
        a1 = as_[(size_t)s1 * 4 + h];
        u1 = *reinterpret_cast<const uint4*>(hp + ((size_t)s1 * 4 + h) * 128 + dim);
    }

    for (int j = e0; j < e1; ++j) {
        float e = a0 + adv;
        uint4 u = u0;
        a0 = a1; u0 = u1;
        if (j + 2 < e1) {
            int sn = csr[j + 2];
            a1 = as_[(size_t)sn * 4 + h];
            u1 = *reinterpret_cast<const uint4*>(hp + ((size_t)sn * 4 + h) * 128 + dim);
        }
        e = e >= 0.f ? e : 0.2f * e;
        float mn = fmaxf(m, e);
        float rs = __expf(m - mn);   // first iter: exp(-inf)=0
        float w  = __expf(e - mn);
        l = l * rs + w;
        float x[8];
        bf2x(u.x, x[0], x[1]);
        bf2x(u.y, x[2], x[3]);
        bf2x(u.z, x[4], x[5]);
        bf2x(u.w, x[6], x[7]);
        #pragma unroll
        for (int t = 0; t < 8; ++t) acc[t] = fmaf(acc[t], rs, w * x[t]);
        m = mn;
    }

    float inv = 1.f / (l + 1e-16f);
    const int ob = h * 128 + dim;
    float v[8];
    #pragma unroll
    for (int t = 0; t < 8; ++t) {
        float z = acc[t] * inv + bias[ob + t];
        v[t] = z >= 0.f ? z : 0.01f * z;
    }
    uint4 o;
    o.x = packbf(v[0], v[1]);
    o.y = packbf(v[2], v[3]);
    o.z = packbf(v[4], v[5]);
    o.w = packbf(v[6], v[7]);
    *reinterpret_cast<uint4*>(out + (size_t)d * 512 + ob) = o;
}

// ---------------------------------------------------------------------------
// GAT aggregation, HEADS=1: one wave per dst, lane owns 2 dims (4B/lane).
// Same depth-2 pipeline.
// ---------------------------------------------------------------------------
__launch_bounds__(256)
__global__ void k_gat_agg_h1(const u16* __restrict__ hp,
                             const float* __restrict__ as_, const float* __restrict__ ad_,
                             const int* __restrict__ rowstart, const int* __restrict__ csr,
                             const float* __restrict__ bias, u16* __restrict__ out, int Nn)
{
    int d = (int)((blockIdx.x * (size_t)blockDim.x + threadIdx.x) >> 6);
    int lane = threadIdx.x & 63;
    if (d >= Nn) return;
    const int dim = lane * 2;
    int e0 = rowstart[d], e1 = rowstart[d + 1];
    float adv = ad_[d];
    float m = -INF_F, l = 0.f, acc0 = 0.f, acc1 = 0.f;

    int s0 = csr[e0];
    float a0 = as_[s0];
    unsigned int u0 = *reinterpret_cast<const unsigned int*>(hp + (size_t)s0 * 128 + dim);
    float a1 = 0.f; unsigned int u1 = u0;
    if (e0 + 1 < e1) {
        int s1 = csr[e0 + 1];
        a1 = as_[s1];
        u1 = *reinterpret_cast<const unsigned int*>(hp + (size_t)s1 * 128 + dim);
    }

    for (int j = e0; j < e1; ++j) {
        float e = a0 + adv;
        unsigned int u = u0;
        a0 = a1; u0 = u1;
        if (j + 2 < e1) {
            int sn = csr[j + 2];
            a1 = as_[sn];
            u1 = *reinterpret_cast<const unsigned int*>(hp + (size_t)sn * 128 + dim);
        }
        e = e >= 0.f ? e : 0.2f * e;
        float mn = fmaxf(m, e);
        float rs = __expf(m - mn);
        float w  = __expf(e - mn);
        float x0, x1;
        bf2x(u, x0, x1);
        l    = l * rs + w;
        acc0 = fmaf(acc0, rs, w * x0);
        acc1 = fmaf(acc1, rs, w * x1);
        m = mn;
    }

    float inv = 1.f / (l + 1e-16f);
    float v0 = acc0 * inv + bias[dim];
    float v1 = acc1 * inv + bias[dim + 1];
    v0 = v0 >= 0.f ? v0 : 0.01f * v0;
    v1 = v1 >= 0.f ? v1 : 0.01f * v1;
    *reinterpret_cast<unsigned int*>(out + (size_t)d * 128 + dim) = packbf(v0, v1);
}

// ---------------------------------------------------------------------------
// Final: z = [bn1(h1)|bn2(h2)|bn3(h3)] @ W + b, then log_softmax over 40 cols.
// BM=64 rows/block, all 40 cols in one block (padded to 64). out fp32.
// ---------------------------------------------------------------------------
__launch_bounds__(256)
__global__ void k_final(const u16* __restrict__ h1, const u16* __restrict__ h2,
                        const u16* __restrict__ h3,
                        const float* __restrict__ scale768, const float* __restrict__ shift768,
                        const float* __restrict__ W, const float* __restrict__ bias,
                        float* __restrict__ out, int M)
{
    __shared__ float As[16][68];
    __shared__ float Bs[16][64];
    const int tid = threadIdx.x;
    const int tx = tid & 15, ty = tid >> 4;
    const int row0 = blockIdx.x * 64;
    const int ar = tid >> 2, ak = (tid & 3) << 2;
    const int bc = (tid & 15) << 2, bk = tid >> 4;
    float acc[4][4] = {};

    for (int k0 = 0; k0 < 768; k0 += 16) {
        const u16* src; int ld, coff;
        if (k0 < 128)      { src = h1; ld = 128; coff = k0; }
        else if (k0 < 640) { src = h2; ld = 512; coff = k0 - 128; }
        else               { src = h3; ld = 128; coff = k0 - 640; }
        {
            int grow = row0 + ar;
            float4 v = make_float4(0.f, 0.f, 0.f, 0.f);
            if (grow < M) {
                ushort4 u = *reinterpret_cast<const ushort4*>(src + (size_t)grow * ld + coff + ak);
                v = make_float4(b2f(u.x), b2f(u.y), b2f(u.z), b2f(u.w));
            }
            int kk = k0 + ak;
            v.x = fmaf(v.x, scale768[kk + 0], shift768[kk + 0]);
            v.y = fmaf(v.y, scale768[kk + 1], shift768[kk + 1]);
            v.z = fmaf(v.z, scale768[kk + 2], shift768[kk + 2]);
            v.w = fmaf(v.w, scale768[kk + 3], shift768[kk + 3]);
            As[ak + 0][ar] = v.x;
            As[ak + 1][ar] = v.y;
            As[ak + 2][ar] = v.z;
            As[ak + 3][ar] = v.w;
        }
        {
            float4 v = make_float4(0.f, 0.f, 0.f, 0.f);
            if (bc < 40)   // cols 40..63 stay zero; W rows are 160B -> 16B aligned
                v = *reinterpret_cast<const float4*>(W + (size_t)(k0 + bk) * 40 + bc);
            *reinterpret_cast<float4*>(&Bs[bk][bc]) = v;
        }
        __syncthreads();
        #pragma unroll
        for (int k = 0; k < 16; ++k) {
            float4 a = *reinterpret_cast<const float4*>(&As[k][ty << 2]);
            float4 b = *reinterpret_cast<const float4*>(&Bs[k][tx << 2]);
            float av[4] = {a.x, a.y, a.z, a.w};
            float bv[4] = {b.x, b.y, b.z, b.w};
            #pragma unroll
            for (int i = 0; i < 4; ++i)
                #pragma unroll
                for (int j = 0; j < 4; ++j)
                    acc[i][j] = fmaf(av[i], bv[j], acc[i][j]);
        }
        __syncthreads();
    }

    // epilogue: bias + log_softmax across the 16 tx-threads (same wave)
    #pragma unroll
    for (int i = 0; i < 4; ++i) {
        float z[4];
        float mx = -INF_F;
        #pragma unroll
        for (int j = 0; j < 4; ++j) {
            int c = (tx << 2) + j;
            float v = acc[i][j] + (c < 40 ? bias[c] : 0.f);
            z[j] = (c < 40) ? v : -INF_F;
            mx = fmaxf(mx, z[j]);
        }
        #pragma unroll
        for (int off = 1; off < 16; off <<= 1) mx = fmaxf(mx, __shfl_xor(mx, off, 64));
        float se = 0.f;
        #pragma unroll
        for (int j = 0; j < 4; ++j) se += __expf(z[j] - mx);   // exp(-inf)=0 for pad
        #pragma unroll
        for (int off = 1; off < 16; off <<= 1) se += __shfl_xor(se, off, 64);
        float lse = mx + __logf(se);
        int r = row0 + (ty << 2) + i;
        if (r < M) {
            #pragma unroll
            for (int j = 0; j < 4; ++j) {
                int c = (tx << 2) + j;
                if (c < 40) out[(size_t)r * 40 + c] = z[j] - lse;
            }
        }
    }
}

// ---------------------------------------------------------------------------
extern "C" void kernel_launch(void* const* d_in, const int* in_sizes, int n_in,
                              void* d_out, int out_size, void* d_ws, size_t ws_size,
                              hipStream_t stream)
{
    const float* x     = (const float*)d_in[0];
    const int*   ei    = (const int*)  d_in[1];
    const float* fw_W  = (const float*)d_in[2];
    const float* fw_b  = (const float*)d_in[3];
    const float* c1_W  = (const float*)d_in[4];
    const float* c1_as = (const float*)d_in[5];
    const float* c1_ad = (const float*)d_in[6];
    const float* c1_b  = (const float*)d_in[7];
    const float* c2_W  = (const float*)d_in[8];
    const float* c2_as = (const float*)d_in[9];
    const float* c2_ad = (const float*)d_in[10];
    const float* c2_b  = (const float*)d_in[11];
    const float* bn1_g = (const float*)d_in[12];
    const float* bn1_b = (const float*)d_in[13];
    const float* bn2_g = (const float*)d_in[14];
    const float* bn2_b = (const float*)d_in[15];
    const float* bn3_g = (const float*)d_in[16];
    const float* bn3_b = (const float*)d_in[17];
    const float* l2_W  = (const float*)d_in[18];
    const float* l2_b  = (const float*)d_in[19];
    float* out = (float*)d_out;

    const int N = in_sizes[0] / 256;   // 50000
    const int E = in_sizes[1] / 2;     // 850000
    const int NB = 256;                // colstats stage-1 blocks

    char* base = (char*)d_ws;
    size_t off = 0;
    auto alloc = [&](size_t bytes) -> void* {
        void* p = (void*)(base + off);
        off = (off + bytes + 255) & ~(size_t)255;
        return p;
    };
    // --- zeroed region (counts, fill, alpha accumulators) ---
    int*   counts = (int*)  alloc((size_t)N * 4);
    int*   fill   = (int*)  alloc((size_t)N * 4);
    float* as1    = (float*)alloc((size_t)N * 4 * 4);
    float* ad1    = (float*)alloc((size_t)N * 4 * 4);
    float* as2    = (float*)alloc((size_t)N * 4);
    float* ad2    = (float*)alloc((size_t)N * 4);
    size_t zero_bytes = off;
    // --- rest (bf16 activations; hp1 region reused for hp2/h3) ---
    float* psum     = (float*)alloc((size_t)NB * 512 * 4);
    float* psq      = (float*)alloc((size_t)NB * 512 * 4);
    int*   rowstart = (int*)  alloc((size_t)(N + 1) * 4);
    int*   csr      = (int*)  alloc((size_t)E * 4);
    float* scale768 = (float*)alloc(768 * 4);
    float* shift768 = (float*)alloc(768 * 4);
    u16*   h1       = (u16*)  alloc((size_t)N * 128 * 2);
    u16*   h2       = (u16*)  alloc((size_t)N * 512 * 2);
    u16*   hp1      = (u16*)  alloc((size_t)N * 512 * 2);  // dead after agg1:
    u16*   hp2      = hp1;                                  //  reuse for hp2 [N,128]
    u16*   h3       = hp1 + (size_t)N * 128;                //  and h3 [N,128]
    (void)ws_size; (void)n_in; (void)out_size;

    const int mb = (N + 63) / 64;
    const int wave_blocks = (int)(((size_t)N * 64 + 255) / 256);

    hipMemsetAsync(base, 0, zero_bytes, stream);

    // layer 1: h1 = lrelu(x @ fw_W + fw_b)
    k_gemm<false, false, true, true, false><<<dim3(2, mb), 256, 0, stream>>>(
        x, 256, fw_W, 128, h1, N, 256, nullptr, nullptr, fw_b, 0.01f,
        nullptr, nullptr, nullptr, nullptr, 0);

    // CSR build (independent)
    k_count<<<(E + 255) / 256, 256, 0, stream>>>(ei + E, E, counts);
    k_scan<<<1, 1024, 0, stream>>>(counts, rowstart, N);
    k_scatter<<<(E + 255) / 256, 256, 0, stream>>>(ei, E, rowstart, fill, csr);

    // BN1
    k_colstats<<<NB, 256, 0, stream>>>(h1, N, 128, psum, psq);
    k_colred<<<(128 + 3) / 4, 256, 0, stream>>>(psum, psq, bn1_g, bn1_b, NB, N, 128,
                                                scale768, shift768);

    // conv1 projection: hp1 = bn1(h1) @ c1_W  [N,512], alpha fused into epilogue
    k_gemm<true, true, false, false, true><<<dim3(8, mb), 256, 0, stream>>>(
        h1, 128, c1_W, 512, hp1, N, 128, scale768, shift768, nullptr, 0.f,
        c1_as, c1_ad, as1, ad1, 4);
    k_gat_agg_h4<<<wave_blocks, 256, 0, stream>>>(
        hp1, as1, ad1, rowstart, csr, c1_b, h2, N);

    // BN2
    k_colstats<<<NB, 256, 0, stream>>>(h2, N, 512, psum, psq);
    k_colred<<<(512 + 3) / 4, 256, 0, stream>>>(psum, psq, bn2_g, bn2_b, NB, N, 512,
                                                scale768 + 128, shift768 + 128);

    // conv2 projection: hp2 = bn2(h2) @ c2_W  [N,128] (into dead hp1 region)
    k_gemm<true, true, false, false, true><<<dim3(2, mb), 256, 0, stream>>>(
        h2, 512, c2_W, 128, hp2, N, 512, scale768 + 128, shift768 + 128, nullptr, 0.f,
        c2_as, c2_ad, as2, ad2, 1);
    k_gat_agg_h1<<<wave_blocks, 256, 0, stream>>>(
        hp2, as2, ad2, rowstart, csr, c2_b, h3, N);

    // BN3
    k_colstats<<<NB, 256, 0, stream>>>(h3, N, 128, psum, psq);
    k_colred<<<(128 + 3) / 4, 256, 0, stream>>>(psum, psq, bn3_g, bn3_b, NB, N, 128,
                                                scale768 + 640, shift768 + 640);

    // final fused GEMM + log_softmax
    k_final<<<mb, 256, 0, stream>>>(h1, h2, h3, scale768, shift768, l2_W, l2_b, out, N);
}

// Round 5
// 585.243 us; speedup vs baseline: 2.4830x; 1.2741x over previous
//
#include <hip/hip_runtime.h>

#define INF_F __builtin_inff()

typedef unsigned short u16;
typedef __attribute__((ext_vector_type(8))) short s16x8;   // 8 bf16 (4 VGPRs)
typedef __attribute__((ext_vector_type(4))) float f32x4;   // MFMA accum

union U8 { uint4 q; s16x8 v; };

__device__ __forceinline__ float b2f(u16 u) {
    union { unsigned int i; float f; } v; v.i = ((unsigned int)u) << 16; return v.f;
}
__device__ __forceinline__ u16 f2b(float f) {
    union { float f; unsigned int i; } v; v.f = f;
    unsigned int r = (v.i + 0x7FFFu + ((v.i >> 16) & 1u)) >> 16;
    return (u16)r;
}
__device__ __forceinline__ void bf2x(unsigned int p, float& lo, float& hi) {
    union { unsigned int i; float f; } a, b;
    a.i = p << 16; b.i = p & 0xFFFF0000u;
    lo = a.f; hi = b.f;
}
__device__ __forceinline__ unsigned int packbf(float lo, float hi) {
    return (unsigned int)f2b(lo) | ((unsigned int)f2b(hi) << 16);
}

// ---------------------------------------------------------------------------
// Pack a fp32 weight [K][N] into bf16 MFMA-B-fragment layout, N padded to Npad
// (pad cols = 0). Element (k,n) -> pb[((n>>4)*(K/32) + (k>>5))*512
//                                     + ((k>>3)&3)*128 + (n&15)*8 + (k&7)].
// A wave then reads frag (colblock cb, kblock k5) as contiguous 1KB at
// pb + (cb*(K/32)+k5)*512 + lane*8.
// ---------------------------------------------------------------------------
__launch_bounds__(256)
__global__ void k_packB(const float* __restrict__ W, int K, int N, int Npad,
                        u16* __restrict__ pb)
{
    int idx = blockIdx.x * 256 + threadIdx.x;
    if (idx >= K * Npad) return;
    int k = idx / Npad, n = idx - k * Npad;
    float v = (n < N) ? W[(size_t)k * N + n] : 0.f;
    int K5 = K >> 5;
    size_t o = ((size_t)(n >> 4) * K5 + (k >> 5)) * 512
             + ((size_t)((k >> 3) & 3)) * 128 + (n & 15) * 8 + (k & 7);
    pb[o] = f2b(v);
}

// ---------------------------------------------------------------------------
// MFMA GEMM: C(bf16) = act(A' @ B [+bias]); A'[r,k]=A[r,k]*scale[k]+shift[k].
// No LDS / no barriers: wave w owns rows [row0+16w,+16); B frags read from
// packed pb (L2-resident); A frag = one 16B(bf16)/32B(fp32) load per lane.
// grid.x splits columns in NFRAG*16 chunks (cb0 = blockIdx.x*NFRAG).
// HEADS_PB>0: fused GAT alpha epilogue (head width = 128 cols, deterministic).
// ---------------------------------------------------------------------------
template<int NFRAG, bool A_FP32, bool BN_A, bool BIAS, bool LRELU, int HEADS_PB>
__launch_bounds__(256)
__global__ void k_mgemm(const void* __restrict__ Av, int lda, int K,
                        const u16* __restrict__ pb,
                        u16* __restrict__ C, int ldc, int M,
                        const float* __restrict__ scale, const float* __restrict__ shift,
                        const float* __restrict__ bias,
                        const float* __restrict__ aw_s, const float* __restrict__ aw_d,
                        float* __restrict__ as_o, float* __restrict__ ad_o, int nheads)
{
    const int tid = threadIdx.x;
    const int w = tid >> 6, l = tid & 63;
    const int lo = l & 15, hi = l >> 4;
    const int row0 = blockIdx.y * 64 + w * 16;
    if (row0 >= M) return;
    const int cb0 = blockIdx.x * NFRAG;
    const int K5 = K >> 5;

    f32x4 acc[NFRAG];
    #pragma unroll
    for (int i = 0; i < NFRAG; ++i) acc[i] = (f32x4){0.f, 0.f, 0.f, 0.f};

    int arow = row0 + lo; if (arow >= M) arow = M - 1;

    for (int k5 = 0; k5 < K5; ++k5) {
        const int ak = k5 * 32 + hi * 8;
        float x[8];
        if (A_FP32) {
            const float* A = (const float*)Av + (size_t)arow * lda + ak;
            float4 v0 = *reinterpret_cast<const float4*>(A);
            float4 v1 = *reinterpret_cast<const float4*>(A + 4);
            x[0]=v0.x; x[1]=v0.y; x[2]=v0.z; x[3]=v0.w;
            x[4]=v1.x; x[5]=v1.y; x[6]=v1.z; x[7]=v1.w;
        } else {
            uint4 q = *reinterpret_cast<const uint4*>((const u16*)Av + (size_t)arow * lda + ak);
            bf2x(q.x, x[0], x[1]); bf2x(q.y, x[2], x[3]);
            bf2x(q.z, x[4], x[5]); bf2x(q.w, x[6], x[7]);
        }
        if (BN_A) {
            #pragma unroll
            for (int j = 0; j < 8; ++j) x[j] = fmaf(x[j], scale[ak + j], shift[ak + j]);
        }
        U8 au;
        au.q.x = packbf(x[0], x[1]); au.q.y = packbf(x[2], x[3]);
        au.q.z = packbf(x[4], x[5]); au.q.w = packbf(x[6], x[7]);
        s16x8 af = au.v;
        #pragma unroll
        for (int cb = 0; cb < NFRAG; ++cb) {
            s16x8 bf = *reinterpret_cast<const s16x8*>(
                pb + ((size_t)(cb0 + cb) * K5 + k5) * 512 + l * 8);
            acc[cb] = __builtin_amdgcn_mfma_f32_16x16x32_bf16(af, bf, acc[cb], 0, 0, 0);
        }
    }

    // C store: D lane layout col=lo, row=hi*4+p
    #pragma unroll
    for (int cb = 0; cb < NFRAG; ++cb) {
        int col = (cb0 + cb) * 16 + lo;
        #pragma unroll
        for (int p = 0; p < 4; ++p) {
            int r = row0 + hi * 4 + p;
            if (r < M) {
                float v = acc[cb][p];
                if (BIAS)  v += bias[col];
                if (LRELU) v = v >= 0.f ? v : 0.01f * v;
                C[(size_t)r * ldc + col] = f2b(v);
            }
        }
    }

    if (HEADS_PB > 0) {
        const int CBH = NFRAG / HEADS_PB;   // 8 col-frags per head (head width 128)
        #pragma unroll
        for (int hl = 0; hl < HEADS_PB; ++hl) {
            float ps[4] = {0.f,0.f,0.f,0.f}, pd[4] = {0.f,0.f,0.f,0.f};
            #pragma unroll
            for (int cc = 0; cc < CBH; ++cc) {
                int cb = hl * CBH + cc;
                int col = (cb0 + cb) * 16 + lo;
                float ws = aw_s[col], wd = aw_d[col];
                #pragma unroll
                for (int p = 0; p < 4; ++p) {
                    ps[p] = fmaf(acc[cb][p], ws, ps[p]);
                    pd[p] = fmaf(acc[cb][p], wd, pd[p]);
                }
            }
            #pragma unroll
            for (int m = 1; m < 16; m <<= 1) {
                #pragma unroll
                for (int p = 0; p < 4; ++p) {
                    ps[p] += __shfl_xor(ps[p], m, 64);
                    pd[p] += __shfl_xor(pd[p], m, 64);
                }
            }
            if (lo == 0) {
                int h = (cb0 >> 3) + hl;
                #pragma unroll
                for (int p = 0; p < 4; ++p) {
                    int r = row0 + hi * 4 + p;
                    if (r < M) {
                        as_o[(size_t)r * nheads + h] = ps[p];
                        ad_o[(size_t)r * nheads + h] = pd[p];
                    }
                }
            }
        }
    }
}

// ---------------------------------------------------------------------------
// Final MFMA GEMM over concat [bn1(h1)|bn2(h2)|bn3(h3)] (K=768) with packed
// l2_W (40 cols zero-padded to 64), fused bias + log_softmax. out fp32 [M,40].
// ---------------------------------------------------------------------------
__launch_bounds__(256)
__global__ void k_mfinal(const u16* __restrict__ h1, const u16* __restrict__ h2,
                         const u16* __restrict__ h3,
                         const float* __restrict__ scale, const float* __restrict__ shift,
                         const u16* __restrict__ pb, const float* __restrict__ bias,
                         float* __restrict__ out, int M)
{
    const int tid = threadIdx.x;
    const int w = tid >> 6, l = tid & 63;
    const int lo = l & 15, hi = l >> 4;
    const int row0 = blockIdx.x * 64 + w * 16;
    if (row0 >= M) return;
    const int K5 = 24;   // 768/32

    f32x4 acc[4];
    #pragma unroll
    for (int i = 0; i < 4; ++i) acc[i] = (f32x4){0.f, 0.f, 0.f, 0.f};

    int arow = row0 + lo; if (arow >= M) arow = M - 1;

    for (int k5 = 0; k5 < K5; ++k5) {
        const int kk = k5 * 32 + hi * 8;   // region-uniform per k5 (32-aligned splits)
        const u16* src; int ld, offk;
        if (kk < 128)      { src = h1; ld = 128; offk = kk; }
        else if (kk < 640) { src = h2; ld = 512; offk = kk - 128; }
        else               { src = h3; ld = 128; offk = kk - 640; }
        uint4 q = *reinterpret_cast<const uint4*>(src + (size_t)arow * ld + offk);
        float x[8];
        bf2x(q.x, x[0], x[1]); bf2x(q.y, x[2], x[3]);
        bf2x(q.z, x[4], x[5]); bf2x(q.w, x[6], x[7]);
        #pragma unroll
        for (int j = 0; j < 8; ++j) x[j] = fmaf(x[j], scale[kk + j], shift[kk + j]);
        U8 au;
        au.q.x = packbf(x[0], x[1]); au.q.y = packbf(x[2], x[3]);
        au.q.z = packbf(x[4], x[5]); au.q.w = packbf(x[6], x[7]);
        s16x8 af = au.v;
        #pragma unroll
        for (int cb = 0; cb < 4; ++cb) {
            s16x8 bf = *reinterpret_cast<const s16x8*>(pb + ((size_t)cb * K5 + k5) * 512 + l * 8);
            acc[cb] = __builtin_amdgcn_mfma_f32_16x16x32_bf16(af, bf, acc[cb], 0, 0, 0);
        }
    }

    // bias + log_softmax over 40 valid cols (cb2 valid iff lo<8; cb3 all pad)
    #pragma unroll
    for (int p = 0; p < 4; ++p) {
        int r = row0 + hi * 4 + p;
        float z0 = acc[0][p] + bias[lo];
        float z1 = acc[1][p] + bias[16 + lo];
        float z2 = -INF_F;
        if (lo < 8) z2 = acc[2][p] + bias[32 + lo];
        float mx = fmaxf(fmaxf(z0, z1), z2);
        #pragma unroll
        for (int m = 1; m < 16; m <<= 1) mx = fmaxf(mx, __shfl_xor(mx, m, 64));
        float se = __expf(z0 - mx) + __expf(z1 - mx) + ((lo < 8) ? __expf(z2 - mx) : 0.f);
        #pragma unroll
        for (int m = 1; m < 16; m <<= 1) se += __shfl_xor(se, m, 64);
        float lse = mx + __logf(se);
        if (r < M) {
            out[(size_t)r * 40 + lo]      = z0 - lse;
            out[(size_t)r * 40 + 16 + lo] = z1 - lse;
            if (lo < 8) out[(size_t)r * 40 + 32 + lo] = z2 - lse;
        }
    }
}

// ---------------------------------------------------------------------------
// BN stats stage 1: per-block column partial sums/sumsq of bf16 matrix.
// ---------------------------------------------------------------------------
__launch_bounds__(256)
__global__ void k_colstats(const u16* __restrict__ X, int M, int C,
                           float* __restrict__ psum, float* __restrict__ psq)
{
    const int CG  = C >> 3;
    const int RPI = 256 / CG;
    const int tid = threadIdx.x;
    const int cg  = tid & (CG - 1);
    const int ro  = tid / CG;
    const int nb  = gridDim.x;
    const int rows_chunk = (M + nb - 1) / nb;
    const int r0 = blockIdx.x * rows_chunk;
    const int r1 = min(M, r0 + rows_chunk);

    float s[8] = {}, q[8] = {};
    for (int r = r0 + ro; r < r1; r += RPI) {
        uint4 u = *reinterpret_cast<const uint4*>(X + (size_t)r * C + cg * 8);
        float x[8];
        bf2x(u.x, x[0], x[1]); bf2x(u.y, x[2], x[3]);
        bf2x(u.z, x[4], x[5]); bf2x(u.w, x[6], x[7]);
        #pragma unroll
        for (int j = 0; j < 8; ++j) { s[j] += x[j]; q[j] = fmaf(x[j], x[j], q[j]); }
    }

    __shared__ float lsum[8][256];
    __shared__ float lsq [8][256];
    #pragma unroll
    for (int j = 0; j < 8; ++j) { lsum[j][tid] = s[j]; lsq[j][tid] = q[j]; }
    __syncthreads();

    if (tid < CG) {
        #pragma unroll
        for (int j = 0; j < 8; ++j) {
            float ss = 0.f, qq = 0.f;
            for (int o = 0; o < RPI; ++o) {
                ss += lsum[j][o * CG + tid];
                qq += lsq [j][o * CG + tid];
            }
            psum[(size_t)blockIdx.x * C + tid * 8 + j] = ss;
            psq [(size_t)blockIdx.x * C + tid * 8 + j] = qq;
        }
    }
}

__launch_bounds__(256)
__global__ void k_colred(const float* __restrict__ psum, const float* __restrict__ psq,
                         const float* __restrict__ g, const float* __restrict__ b,
                         int nb, int M, int C,
                         float* __restrict__ scale, float* __restrict__ shift)
{
    int c = blockIdx.x * 4 + (threadIdx.x >> 6);
    int lane = threadIdx.x & 63;
    if (c >= C) return;
    float s = 0.f, q = 0.f;
    for (int l = lane; l < nb; l += 64) {
        s += psum[(size_t)l * C + c];
        q += psq [(size_t)l * C + c];
    }
    #pragma unroll
    for (int off = 32; off; off >>= 1) {
        s += __shfl_xor(s, off, 64);
        q += __shfl_xor(q, off, 64);
    }
    if (lane == 0) {
        float mu  = s / (float)M;
        float var = q / (float)M - mu * mu;
        float sc  = g[c] * rsqrtf(var + 1e-5f);
        scale[c] = sc;
        shift[c] = b[c] - mu * sc;
    }
}

// ---------------------------------------------------------------------------
// CSR build: count -> scan -> scatter
// ---------------------------------------------------------------------------
__launch_bounds__(256)
__global__ void k_count(const int* __restrict__ dst, int E, int* __restrict__ counts)
{
    int e = blockIdx.x * 256 + threadIdx.x;
    if (e < E) atomicAdd(&counts[dst[e]], 1);
}

__launch_bounds__(1024)
__global__ void k_scan(const int* __restrict__ counts, int* __restrict__ rowstart, int n)
{
    __shared__ int wsum[16];
    __shared__ int s_carry;
    int tid = threadIdx.x, lane = tid & 63, w = tid >> 6;
    if (tid == 0) { s_carry = 0; rowstart[0] = 0; }
    __syncthreads();
    for (int base = 0; base < n; base += 1024) {
        int carry = s_carry;
        int v = (base + tid < n) ? counts[base + tid] : 0;
        int x = v;
        #pragma unroll
        for (int off = 1; off < 64; off <<= 1) {
            int t = __shfl_up(x, off, 64);
            if (lane >= off) x += t;
        }
        if (lane == 63) wsum[w] = x;
        __syncthreads();
        int woff = 0;
        #pragma unroll
        for (int i = 0; i < 16; ++i)
            if (i < w) woff += wsum[i];
        int incl = carry + woff + x;
        if (base + tid < n) rowstart[base + tid + 1] = incl;
        __syncthreads();
        if (tid == 1023) s_carry = incl;
        __syncthreads();
    }
}

__launch_bounds__(256)
__global__ void k_scatter(const int* __restrict__ ei, int E,
                          const int* __restrict__ rowstart,
                          int* __restrict__ fill, int* __restrict__ csr)
{
    int e = blockIdx.x * 256 + threadIdx.x;
    if (e >= E) return;
    int s = ei[e], d = ei[E + e];
    int pos = rowstart[d] + atomicAdd(&fill[d], 1);
    csr[pos] = s;
}

// ---------------------------------------------------------------------------
// GAT aggregation, HEADS=4: one wave per dst covers all heads.
// ---------------------------------------------------------------------------
__launch_bounds__(256)
__global__ void k_gat_agg_h4(const u16* __restrict__ hp,
                             const float* __restrict__ as_, const float* __restrict__ ad_,
                             const int* __restrict__ rowstart, const int* __restrict__ csr,
                             const float* __restrict__ bias, u16* __restrict__ out, int Nn)
{
    int d = (int)((blockIdx.x * (size_t)blockDim.x + threadIdx.x) >> 6);
    int lane = threadIdx.x & 63;
    if (d >= Nn) return;
    const int h = lane >> 4;
    const int dim = (lane & 15) * 8;
    int e0 = rowstart[d], e1 = rowstart[d + 1];
    float adv = ad_[(size_t)d * 4 + h];
    float m = -INF_F, l = 0.f;
    float acc[8] = {};

    int s0 = csr[e0];
    float a0 = as_[(size_t)s0 * 4 + h];
    uint4 u0 = *reinterpret_cast<const uint4*>(hp + ((size_t)s0 * 4 + h) * 128 + dim);
    float a1 = 0.f; uint4 u1 = u0;
    if (e0 + 1 < e1) {
        int s1 = csr[e0 + 1];
        a1 = as_[(size_t)s1 * 4 + h];
        u1 = *reinterpret_cast<const uint4*>(hp + ((size_t)s1 * 4 + h) * 128 + dim);
    }

    for (int j = e0; j < e1; ++j) {
        float e = a0 + adv;
        uint4 u = u0;
        a0 = a1; u0 = u1;
        if (j + 2 < e1) {
            int sn = csr[j + 2];
            a1 = as_[(size_t)sn * 4 + h];
            u1 = *reinterpret_cast<const uint4*>(hp + ((size_t)sn * 4 + h) * 128 + dim);
        }
        e = e >= 0.f ? e : 0.2f * e;
        float mn = fmaxf(m, e);
        float rs = __expf(m - mn);
        float w  = __expf(e - mn);
        l = l * rs + w;
        float x[8];
        bf2x(u.x, x[0], x[1]); bf2x(u.y, x[2], x[3]);
        bf2x(u.z, x[4], x[5]); bf2x(u.w, x[6], x[7]);
        #pragma unroll
        for (int t = 0; t < 8; ++t) acc[t] = fmaf(acc[t], rs, w * x[t]);
        m = mn;
    }

    float inv = 1.f / (l + 1e-16f);
    const int ob = h * 128 + dim;
    float v[8];
    #pragma unroll
    for (int t = 0; t < 8; ++t) {
        float z = acc[t] * inv + bias[ob + t];
        v[t] = z >= 0.f ? z : 0.01f * z;
    }
    uint4 o;
    o.x = packbf(v[0], v[1]); o.y = packbf(v[2], v[3]);
    o.z = packbf(v[4], v[5]); o.w = packbf(v[6], v[7]);
    *reinterpret_cast<uint4*>(out + (size_t)d * 512 + ob) = o;
}

// ---------------------------------------------------------------------------
// GAT aggregation, HEADS=1.
// ---------------------------------------------------------------------------
__launch_bounds__(256)
__global__ void k_gat_agg_h1(const u16* __restrict__ hp,
                             const float* __restrict__ as_, const float* __restrict__ ad_,
                             const int* __restrict__ rowstart, const int* __restrict__ csr,
                             const float* __restrict__ bias, u16* __restrict__ out, int Nn)
{
    int d = (int)((blockIdx.x * (size_t)blockDim.x + threadIdx.x) >> 6);
    int lane = threadIdx.x & 63;
    if (d >= Nn) return;
    const int dim = lane * 2;
    int e0 = rowstart[d], e1 = rowstart[d + 1];
    float adv = ad_[d];
    float m = -INF_F, l = 0.f, acc0 = 0.f, acc1 = 0.f;

    int s0 = csr[e0];
    float a0 = as_[s0];
    unsigned int u0 = *reinterpret_cast<const unsigned int*>(hp + (size_t)s0 * 128 + dim);
    float a1 = 0.f; unsigned int u1 = u0;
    if (e0 + 1 < e1) {
        int s1 = csr[e0 + 1];
        a1 = as_[s1];
        u1 = *reinterpret_cast<const unsigned int*>(hp + (size_t)s1 * 128 + dim);
    }

    for (int j = e0; j < e1; ++j) {
        float e = a0 + adv;
        unsigned int u = u0;
        a0 = a1; u0 = u1;
        if (j + 2 < e1) {
            int sn = csr[j + 2];
            a1 = as_[sn];
            u1 = *reinterpret_cast<const unsigned int*>(hp + (size_t)sn * 128 + dim);
        }
        e = e >= 0.f ? e : 0.2f * e;
        float mn = fmaxf(m, e);
        float rs = __expf(m - mn);
        float w  = __expf(e - mn);
        float x0, x1;
        bf2x(u, x0, x1);
        l    = l * rs + w;
        acc0 = fmaf(acc0, rs, w * x0);
        acc1 = fmaf(acc1, rs, w * x1);
        m = mn;
    }

    float inv = 1.f / (l + 1e-16f);
    float v0 = acc0 * inv + bias[dim];
    float v1 = acc1 * inv + bias[dim + 1];
    v0 = v0 >= 0.f ? v0 : 0.01f * v0;
    v1 = v1 >= 0.f ? v1 : 0.01f * v1;
    *reinterpret_cast<unsigned int*>(out + (size_t)d * 128 + dim) = packbf(v0, v1);
}

// ---------------------------------------------------------------------------
extern "C" void kernel_launch(void* const* d_in, const int* in_sizes, int n_in,
                              void* d_out, int out_size, void* d_ws, size_t ws_size,
                              hipStream_t stream)
{
    const float* x     = (const float*)d_in[0];
    const int*   ei    = (const int*)  d_in[1];
    const float* fw_W  = (const float*)d_in[2];
    const float* fw_b  = (const float*)d_in[3];
    const float* c1_W  = (const float*)d_in[4];
    const float* c1_as = (const float*)d_in[5];
    const float* c1_ad = (const float*)d_in[6];
    const float* c1_b  = (const float*)d_in[7];
    const float* c2_W  = (const float*)d_in[8];
    const float* c2_as = (const float*)d_in[9];
    const float* c2_ad = (const float*)d_in[10];
    const float* c2_b  = (const float*)d_in[11];
    const float* bn1_g = (const float*)d_in[12];
    const float* bn1_b = (const float*)d_in[13];
    const float* bn2_g = (const float*)d_in[14];
    const float* bn2_b = (const float*)d_in[15];
    const float* bn3_g = (const float*)d_in[16];
    const float* bn3_b = (const float*)d_in[17];
    const float* l2_W  = (const float*)d_in[18];
    const float* l2_b  = (const float*)d_in[19];
    float* out = (float*)d_out;

    const int N = in_sizes[0] / 256;   // 50000
    const int E = in_sizes[1] / 2;     // 850000
    const int NB = 256;

    char* base = (char*)d_ws;
    size_t off = 0;
    auto alloc = [&](size_t bytes) -> void* {
        void* p = (void*)(base + off);
        off = (off + bytes + 255) & ~(size_t)255;
        return p;
    };
    // --- zeroed region (counts, fill) ---
    int*   counts = (int*)  alloc((size_t)N * 4);
    int*   fill   = (int*)  alloc((size_t)N * 4);
    size_t zero_bytes = off;
    // --- rest ---
    float* as1      = (float*)alloc((size_t)N * 4 * 4);
    float* ad1      = (float*)alloc((size_t)N * 4 * 4);
    float* as2      = (float*)alloc((size_t)N * 4);
    float* ad2      = (float*)alloc((size_t)N * 4);
    float* psum     = (float*)alloc((size_t)NB * 512 * 4);
    float* psq      = (float*)alloc((size_t)NB * 512 * 4);
    int*   rowstart = (int*)  alloc((size_t)(N + 1) * 4);
    int*   csr      = (int*)  alloc((size_t)E * 4);
    float* scale768 = (float*)alloc(768 * 4);
    float* shift768 = (float*)alloc(768 * 4);
    u16*   pb_l1    = (u16*)  alloc((size_t)256 * 128 * 2);
    u16*   pb_c1    = (u16*)  alloc((size_t)128 * 512 * 2);
    u16*   pb_c2    = (u16*)  alloc((size_t)512 * 128 * 2);
    u16*   pb_f     = (u16*)  alloc((size_t)768 * 64 * 2);
    u16*   h1       = (u16*)  alloc((size_t)N * 128 * 2);
    u16*   h2       = (u16*)  alloc((size_t)N * 512 * 2);
    u16*   hp1      = (u16*)  alloc((size_t)N * 512 * 2);  // dead after agg1:
    u16*   hp2      = hp1;                                  //  reuse for hp2 [N,128]
    u16*   h3       = hp1 + (size_t)N * 128;                //  and h3 [N,128]
    (void)ws_size; (void)n_in; (void)out_size;

    const int mb = (N + 63) / 64;
    const int wave_blocks = (int)(((size_t)N * 64 + 255) / 256);

    hipMemsetAsync(base, 0, zero_bytes, stream);

    // pack weights into MFMA-B layout (tiny)
    k_packB<<<(256 * 128 + 255) / 256, 256, 0, stream>>>(fw_W, 256, 128, 128, pb_l1);
    k_packB<<<(128 * 512 + 255) / 256, 256, 0, stream>>>(c1_W, 128, 512, 512, pb_c1);
    k_packB<<<(512 * 128 + 255) / 256, 256, 0, stream>>>(c2_W, 512, 128, 128, pb_c2);
    k_packB<<<(768 *  64 + 255) / 256, 256, 0, stream>>>(l2_W, 768,  40,  64, pb_f);

    // CSR build (independent)
    k_count<<<(E + 255) / 256, 256, 0, stream>>>(ei + E, E, counts);
    k_scan<<<1, 1024, 0, stream>>>(counts, rowstart, N);
    k_scatter<<<(E + 255) / 256, 256, 0, stream>>>(ei, E, rowstart, fill, csr);

    // layer 1: h1 = lrelu(x @ fw_W + fw_b)
    k_mgemm<8, true, false, true, true, 0><<<dim3(1, mb), 256, 0, stream>>>(
        x, 256, 256, pb_l1, h1, 128, N, nullptr, nullptr, fw_b,
        nullptr, nullptr, nullptr, nullptr, 0);

    // BN1
    k_colstats<<<NB, 256, 0, stream>>>(h1, N, 128, psum, psq);
    k_colred<<<(128 + 3) / 4, 256, 0, stream>>>(psum, psq, bn1_g, bn1_b, NB, N, 128,
                                                scale768, shift768);

    // conv1 projection: hp1 = bn1(h1) @ c1_W [N,512] + fused alpha (2 heads/block)
    k_mgemm<16, false, true, false, false, 2><<<dim3(2, mb), 256, 0, stream>>>(
        h1, 128, 128, pb_c1, hp1, 512, N, scale768, shift768, nullptr,
        c1_as, c1_ad, as1, ad1, 4);
    k_gat_agg_h4<<<wave_blocks, 256, 0, stream>>>(
        hp1, as1, ad1, rowstart, csr, c1_b, h2, N);

    // BN2
    k_colstats<<<NB, 256, 0, stream>>>(h2, N, 512, psum, psq);
    k_colred<<<(512 + 3) / 4, 256, 0, stream>>>(psum, psq, bn2_g, bn2_b, NB, N, 512,
                                                scale768 + 128, shift768 + 128);

    // conv2 projection: hp2 = bn2(h2) @ c2_W [N,128] + fused alpha (1 head)
    k_mgemm<8, false, true, false, false, 1><<<dim3(1, mb), 256, 0, stream>>>(
        h2, 512, 512, pb_c2, hp2, 128, N, scale768 + 128, shift768 + 128, nullptr,
        c2_as, c2_ad, as2, ad2, 1);
    k_gat_agg_h1<<<wave_blocks, 256, 0, stream>>>(
        hp2, as2, ad2, rowstart, csr, c2_b, h3, N);

    // BN3
    k_colstats<<<NB, 256, 0, stream>>>(h3, N, 128, psum, psq);
    k_colred<<<(128 + 3) / 4, 256, 0, stream>>>(psum, psq, bn3_g, bn3_b, NB, N, 128,
                                                scale768 + 640, shift768 + 640);

    // final fused GEMM + log_softmax
    k_mfinal<<<mb, 256, 0, stream>>>(h1, h2, h3, scale768, shift768, pb_f, l2_b, out, N);
}